// Round 14
// baseline (487.667 us; speedup 1.0000x reference)
//
#include <hip/hip_runtime.h>
#include <hip/hip_bf16.h>
#include <cstdint>

#define P_ 88   // pitches (sequence length of the scan)
#define B_ 16   // batch
#define T_ 256  // timesteps (folded into batch N)
#define H_ 188  // per-pitch features
#define G_ 192  // 4*48 gates; also LSTM1 input size (188 feat + 4 ctx)
#define U_ 48   // LSTM units
#define N_ 4096 // B_*T_

typedef __attribute__((ext_vector_type(8))) short bf16x8;
typedef __attribute__((ext_vector_type(8))) _Float16 f16x8;
typedef __attribute__((ext_vector_type(4))) float f32x4;

__device__ __forceinline__ float sigf(float x) {
  return __builtin_amdgcn_rcpf(1.0f + __expf(-x));
}
__device__ __forceinline__ float tanh_f(float x) {
  return 1.0f - 2.0f * __builtin_amdgcn_rcpf(1.0f + __expf(2.0f * x));
}
__device__ __forceinline__ float hs2f(unsigned short s) {
  union { unsigned short u; _Float16 h; } x;
  x.u = s;
  return (float)x.h;
}
__device__ __forceinline__ unsigned short f2hs(float v) {
  union { _Float16 h; unsigned short s; } x;
  x.h = (_Float16)v;
  return x.s;
}

// Relaxed workgroup barrier: waits only on LDS ops (lgkmcnt), NOT vmcnt.
__device__ __forceinline__ void lds_barrier() {
  asm volatile("s_waitcnt lgkmcnt(0)\n\ts_barrier" ::: "memory");
}

// 4x4 transpose within each quad of lanes (xor-1 then xor-2 butterfly).
// Input: v[r] = value(type = l&3, row r). Output: g[t] = value(type t, row l&3).
__device__ __forceinline__ void qtrans(const f32x4 v, int l,
                                       float& g0, float& g1, float& g2, float& g3) {
  const bool qo = (l & 1);
  const float e0 = __shfl_xor((float)v[1], 1);
  const float e1 = __shfl_xor((float)v[0], 1);
  const float e2 = __shfl_xor((float)v[3], 1);
  const float e3 = __shfl_xor((float)v[2], 1);
  const float a0 = qo ? e0 : v[0];
  const float a1 = qo ? v[1] : e1;
  const float a2 = qo ? e2 : v[2];
  const float a3 = qo ? v[3] : e3;
  const bool q2 = (l & 2);
  const float f0 = __shfl_xor(a2, 2);
  const float f1 = __shfl_xor(a3, 2);
  const float f2 = __shfl_xor(a0, 2);
  const float f3 = __shfl_xor(a1, 2);
  g0 = q2 ? f0 : a0;
  g1 = q2 ? f1 : a1;
  g2 = q2 ? a2 : f2;
  g3 = q2 ? a3 : f3;
}

// ---------------------------------------------------------------------------
// Kernel 1: context MLP -> per-(b,p) gate bias vector
// ---------------------------------------------------------------------------
__global__ void ctx_kernel(const float* __restrict__ pc,
                           const float* __restrict__ fc1w, const float* __restrict__ fc1b,
                           const float* __restrict__ fc2w, const float* __restrict__ fc2b,
                           const float* __restrict__ fc3w, const float* __restrict__ fc3b,
                           const float* __restrict__ wih1,
                           const float* __restrict__ bih1, const float* __restrict__ bhh1,
                           float* __restrict__ ctxg) {
  int bp = blockIdx.x * 64 + threadIdx.x;
  if (bp >= B_ * P_) return;
  float p0 = pc[bp * 3 + 0], p1 = pc[bp * 3 + 1], p2 = pc[bp * 3 + 2];
  float x1[16], x2[16];
#pragma unroll
  for (int jj = 0; jj < 16; ++jj)
    x1[jj] = fmaxf(0.f, fc1w[jj * 3 + 0] * p0 + fc1w[jj * 3 + 1] * p1 + fc1w[jj * 3 + 2] * p2 + fc1b[jj]);
#pragma unroll
  for (int jj = 0; jj < 16; ++jj) {
    float s = fc2b[jj];
#pragma unroll
    for (int i = 0; i < 16; ++i) s += fc2w[jj * 16 + i] * x1[i];
    x2[jj] = fmaxf(0.f, s);
  }
  float ce[4];
#pragma unroll
  for (int jj = 0; jj < 4; ++jj) {
    float s = fc3b[jj];
#pragma unroll
    for (int i = 0; i < 16; ++i) s += fc3w[jj * 16 + i] * x2[i];
    ce[jj] = s;
  }
  float* op = ctxg + (size_t)bp * G_;
  for (int g = 0; g < G_; ++g) {
    const float* wr = wih1 + (size_t)g * G_ + H_;
    op[g] = bih1[g] + bhh1[g] + ce[0] * wr[0] + ce[1] * wr[1] + ce[2] * wr[2] + ce[3] * wr[3];
  }
}

// ---------------------------------------------------------------------------
// Kernel 1b: pack wih1 feature columns into f16 MFMA B-fragment order.
// ---------------------------------------------------------------------------
__global__ __launch_bounds__(256) void wfrag_kernel(const float* __restrict__ wih1,
                                                    f16x8* __restrict__ wfrag) {
  const int idx = blockIdx.x * 256 + threadIdx.x;
  if (idx >= 12 * 6 * 64) return;
  const int l = idx & 63;
  const int kc = (idx >> 6) % 6;
  const int j = idx / 384;
  const int g = j * 16 + (l & 15);
  const int k0 = kc * 32 + (l >> 4) * 8;
  f16x8 v;
#pragma unroll
  for (int e = 0; e < 8; ++e) {
    const int k = k0 + e;
    const float wv = (k < H_) ? wih1[(size_t)g * G_ + k] : 0.f;
    v[e] = (_Float16)wv;
  }
  wfrag[idx] = v;
}

// ---------------------------------------------------------------------------
// Kernel 2: MFMA GEMM (LDS-staged A, LDS-repacked stores). Epilogue scatters
// into the scan's TYPE-INTERLEAVED gate order: gate j = t*48 + w*12 + ul
// lives at (tile w*3 + c/16, col c&15) with c = ul*4 + t.
// ---------------------------------------------------------------------------
__global__ __launch_bounds__(256, 3) void gemm_mfma(const float* __restrict__ pf,
                                                    const f16x8* __restrict__ wfrag,
                                                    const float* __restrict__ ctxg,
                                                    unsigned short* __restrict__ xg2) {
  const int bp = blockIdx.x >> 1, tb = blockIdx.x & 1;
  const int p = bp % P_, b = bp / P_;
  const int tid = threadIdx.x;
  const int w = tid >> 6, l = tid & 63;
  const int lj = l & 15, lq = l >> 4;

  __shared__ __align__(16) char ldsraw[49152];
  _Float16(*Ahi)[34] = (_Float16(*)[34])ldsraw;
  _Float16(*Alo)[34] = (_Float16(*)[34])(ldsraw + 8704);

  float cg[12];
#pragma unroll
  for (int jn = 0; jn < 12; ++jn)
    cg[jn] = ctxg[(size_t)bp * G_ + jn * 16 + lj];

  f32x4 acc[2][12];
#pragma unroll
  for (int mt = 0; mt < 2; ++mt)
#pragma unroll
    for (int jn = 0; jn < 12; ++jn)
#pragma unroll
      for (int r = 0; r < 4; ++r) acc[mt][jn][r] = 0.f;

  const float* Ab = pf + (size_t)bp * H_ * T_ + tb * 128;
  const int kl = tid >> 5;
  const int t4 = (tid & 31) * 4;

  for (int kc = 0; kc < 6; ++kc) {
    __syncthreads();
#pragma unroll
    for (int rr = 0; rr < 4; ++rr) {
      const int kk = rr * 8 + kl;
      const int kg = kc * 32 + kk;
      float a0 = 0.f, a1 = 0.f, a2 = 0.f, a3 = 0.f;
      if (kg < H_) {
        const float4 v = *(const float4*)(Ab + (size_t)kg * T_ + t4);
        a0 = v.x; a1 = v.y; a2 = v.z; a3 = v.w;
      }
      const _Float16 h0 = (_Float16)a0, h1 = (_Float16)a1;
      const _Float16 h2 = (_Float16)a2, h3 = (_Float16)a3;
      Ahi[t4 + 0][kk] = h0; Alo[t4 + 0][kk] = (_Float16)(a0 - (float)h0);
      Ahi[t4 + 1][kk] = h1; Alo[t4 + 1][kk] = (_Float16)(a1 - (float)h1);
      Ahi[t4 + 2][kk] = h2; Alo[t4 + 2][kk] = (_Float16)(a2 - (float)h2);
      Ahi[t4 + 3][kk] = h3; Alo[t4 + 3][kk] = (_Float16)(a3 - (float)h3);
    }
    __syncthreads();
    const int trow = w * 32;
    const f16x8 ahi0 = *(const f16x8*)&Ahi[trow + lj][lq * 8];
    const f16x8 ahi1 = *(const f16x8*)&Ahi[trow + 16 + lj][lq * 8];
    const f16x8 alo0 = *(const f16x8*)&Alo[trow + lj][lq * 8];
    const f16x8 alo1 = *(const f16x8*)&Alo[trow + 16 + lj][lq * 8];
#pragma unroll
    for (int jn = 0; jn < 12; ++jn) {
      const f16x8 wf = wfrag[(jn * 6 + kc) * 64 + l];
      acc[0][jn] = __builtin_amdgcn_mfma_f32_16x16x32_f16(ahi0, wf, acc[0][jn], 0, 0, 0);
      acc[1][jn] = __builtin_amdgcn_mfma_f32_16x16x32_f16(ahi1, wf, acc[1][jn], 0, 0, 0);
      acc[0][jn] = __builtin_amdgcn_mfma_f32_16x16x32_f16(alo0, wf, acc[0][jn], 0, 0, 0);
      acc[1][jn] = __builtin_amdgcn_mfma_f32_16x16x32_f16(alo1, wf, acc[1][jn], 0, 0, 0);
    }
  }
  __syncthreads();

  // epilogue: + ctx bias, f16, scatter into type-interleaved scan order,
  // then uint4 coalesced global stores.
  unsigned short* Cst = (unsigned short*)ldsraw + w * 6144;
#pragma unroll
  for (int mt = 0; mt < 2; ++mt)
#pragma unroll
    for (int jn = 0; jn < 12; ++jn) {
      const int g = jn * 16 + lj;
      const int t = g / 48;
      const int rem = g - 48 * t;
      const int sw = rem / 12;
      const int ul = rem - 12 * sw;
      const int c = ul * 4 + t;
      const int slot = (sw * 3 + (c >> 4)) * 256 + lq * 16 + (c & 15);
#pragma unroll
      for (int r = 0; r < 4; ++r)
        Cst[mt * 3072 + slot + r * 64] = f2hs(acc[mt][jn][r] + cg[jn]);
    }
  const int nb0 = b * 16 + tb * 8 + w * 2;
  unsigned short* gb = xg2 + ((size_t)p * 256 + nb0) * 3072;
#pragma unroll
  for (int rr = 0; rr < 12; ++rr) {
    const uint4 v = *(const uint4*)(Cst + rr * 512 + l * 8);
    *(uint4*)(gb + rr * 512 + l * 8) = v;
  }
}

// ---------------------------------------------------------------------------
// Kernel 3: MFMA persistent scan, 2 barriers/step, IN-REGISTER activation.
// Type-interleaved cols: tile i col cj -> c=i*16+cj, unit ul=c>>2, type t=c&3,
// gate j = t*48 + w*12 + ul. Each quad's C-fragment = {4 types x 4 rows} for
// one unit -> qtrans + activation in-register (no gs LDS round trip).
// h parity-buffered f16 (hbuf[2]); aux roles balanced on lanes>=32 of EVERY
// wave (10 fc + 10 store + 2 softmax per wave).
// ---------------------------------------------------------------------------
__global__ __launch_bounds__(256, 2) void scan_mfma(
    const unsigned short* __restrict__ xg2,
    const float* __restrict__ whh1, const float* __restrict__ wih2,
    const float* __restrict__ whh2, const float* __restrict__ bih2,
    const float* __restrict__ bhh2, const float* __restrict__ fcw,
    const float* __restrict__ fcb, float* __restrict__ out) {
  __shared__ __align__(16) _Float16 hbuf[2][16][120];  // cols 0-47 h1, 48-95 h2
  __shared__ __align__(16) float h2f[2][8][52];        // h2 fp32 (parity) for fc
  __shared__ __align__(16) float fcws[5 * 48];
  __shared__ float logit_s[5][8];
  __shared__ float prob_s[5][8];

  const int tid = threadIdx.x;
  const int w = tid >> 6, l = tid & 63;
  const int lj = l & 15, lq = l >> 4;
  const int grp = blockIdx.x >> 1, half = blockIdx.x & 1;
  const int n0 = blockIdx.x * 8;
  const int b = n0 >> 8, t0 = n0 & 255;

  // ---- persistent weight B-fragments, type-interleaved mapping ----
  f16x8 b1[3][2];
  f16x8 b2f[3][3];
  float bias2r[3];
#pragma unroll
  for (int i = 0; i < 3; ++i) {
    const int c = i * 16 + lj;
    const int ul = c >> 2, t = c & 3;
    const int j = t * 48 + w * 12 + ul;
    bias2r[i] = bih2[j] + bhh2[j];
#pragma unroll
    for (int kc = 0; kc < 2; ++kc)
#pragma unroll
      for (int e = 0; e < 8; ++e) {
        const int u = kc * 32 + lq * 8 + e;
        b1[i][kc][e] = (u < U_) ? (_Float16)whh1[j * U_ + u] : (_Float16)0.f;
      }
#pragma unroll
    for (int kc = 0; kc < 3; ++kc)
#pragma unroll
      for (int e = 0; e < 8; ++e) {
        const int k = kc * 32 + lq * 8 + e;
        b2f[i][kc][e] = (k < U_) ? (_Float16)wih2[j * U_ + k]
                                 : (_Float16)whh2[j * U_ + (k - U_)];
      }
  }

  for (int e = tid; e < 2 * 16 * 120 / 2; e += 256) ((unsigned int*)hbuf)[e] = 0u;
  for (int e = tid; e < 2 * 8 * 52; e += 256) ((float*)h2f)[e] = 0.f;
  for (int e = tid; e < 5 * U_; e += 256) fcws[e] = fcw[e];

  // activation task (lanes l<32): row qn, unit w*12 + i*4 + kk per tile i
  const int qn = lq * 4 + (l & 3);   // valid for l<32 (lq in {0,1})
  const int kk = (l >> 2) & 3;
  float c1s[3] = {0.f, 0.f, 0.f}, c2s[3] = {0.f, 0.f, 0.f};

  // aux roles on lanes >= 32 (balanced across all 4 waves)
  const bool fcth = (l >= 32 && l < 42);
  const int fi = w * 10 + (l - 32);
  const int fk = (fi >> 3) < 5 ? (fi >> 3) : 0, fn = fi & 7;
  const float fcbr = fcth ? fcb[fk] : 0.f;
  const bool stth = (l >= 42 && l < 52);
  const int ts = w * 10 + (l - 42);
  const int sk = (ts >> 3) < 5 ? (ts >> 3) : 0, sn = ts & 7;
  const bool smth = (l >= 52 && l < 54);
  const int smn = w * 2 + (l - 52);

  // xg prefetch for step 0 (lanes lq<2 hold rows half*8 + lq*4+r)
  unsigned short xp[12];
  {
    const size_t pb = (size_t)grp * 3072;
#pragma unroll
    for (int i = 0; i < 3; ++i)
#pragma unroll
      for (int r = 0; r < 4; ++r)
        xp[i * 4 + r] = (lq < 2)
            ? xg2[pb + (size_t)((w * 3 + i) * 256 + r * 64 + (half * 2 + lq) * 16 + lj)]
            : (unsigned short)0;
  }
  lds_barrier();

  for (int p = -1; p < P_; ++p) {
    const int cur = p & 1, alt = cur ^ 1;
    // ============ PHASE A: L2(p) MFMA + in-reg act2 | fc(p-1), store(p-2) ===
    if (p >= 0) {
      const _Float16* hc = &hbuf[cur][lj][0];
      const _Float16* ha = &hbuf[alt][lj][0];
      const f16x8 f0 = *(const f16x8*)(hc + lq * 8);                       // h1(p) k0-31
      const f16x8 f1 = *(const f16x8*)(((lq < 2) ? hc : ha) + 32 + lq * 8); // k32-63 spans h1(p)/h2(p-1)
      const f16x8 f2 = *(const f16x8*)(ha + 64 + lq * 8);                  // h2(p-1) k64-95
      f32x4 dH[3];
#pragma unroll
      for (int i = 0; i < 3; ++i) {
        dH[i][0] = bias2r[i]; dH[i][1] = bias2r[i];
        dH[i][2] = bias2r[i]; dH[i][3] = bias2r[i];
      }
#pragma unroll
      for (int i = 0; i < 3; ++i)
        dH[i] = __builtin_amdgcn_mfma_f32_16x16x32_f16(f0, b2f[i][0], dH[i], 0, 0, 0);
#pragma unroll
      for (int i = 0; i < 3; ++i)
        dH[i] = __builtin_amdgcn_mfma_f32_16x16x32_f16(f1, b2f[i][1], dH[i], 0, 0, 0);
#pragma unroll
      for (int i = 0; i < 3; ++i)
        dH[i] = __builtin_amdgcn_mfma_f32_16x16x32_f16(f2, b2f[i][2], dH[i], 0, 0, 0);
      if (l < 32) {
#pragma unroll
        for (int i = 0; i < 3; ++i) {
          float g0, g1, g2, g3;
          qtrans(dH[i], l, g0, g1, g2, g3);
          const float cc = sigf(g1) * c2s[i] + sigf(g0) * tanh_f(g2);
          c2s[i] = cc;
          const float h = sigf(g3) * tanh_f(cc);
          const int u = w * 12 + i * 4 + kk;
          hbuf[cur][qn][48 + u] = (_Float16)h;   // h2(p) -> buf[cur] (disjoint from reads)
          h2f[cur][qn][u] = h;
        }
      } else if (fcth && p >= 1) {
        float a = fcbr;
#pragma unroll
        for (int uq = 0; uq < 12; ++uq) {
          f32x4 hv = *(const f32x4*)&h2f[alt][fn][uq * 4];
          f32x4 wv = *(const f32x4*)&fcws[fk * 48 + uq * 4];
          a += hv[0] * wv[0] + hv[1] * wv[1] + hv[2] * wv[2] + hv[3] * wv[3];
        }
        logit_s[fk][fn] = a;
      } else if (stth && p >= 2) {
        out[(((size_t)b * P_ + (p - 2)) * 5 + sk) * T_ + t0 + sn] = prob_s[sk][sn];
      }
    }
    lds_barrier();
    // ============ PHASE B: L1(p+1) MFMA + in-reg act1 | softmax(p-1) ========
    if (p < P_ - 1) {
      const _Float16* hc = &hbuf[cur][lj][0];
      const f16x8 f0 = *(const f16x8*)(hc + lq * 8);        // h1(p) k0-31
      const f16x8 f1 = *(const f16x8*)(hc + 32 + lq * 8);   // k32-63 (k>=48: B is zero)
      f32x4 cH[3];
#pragma unroll
      for (int i = 0; i < 3; ++i)
#pragma unroll
        for (int r = 0; r < 4; ++r) cH[i][r] = hs2f(xp[i * 4 + r]);
      if (p < P_ - 2) {  // prefetch xg(p+2); in flight across barriers
        const size_t pb = (size_t)((p + 2) * 256 + grp) * 3072;
#pragma unroll
        for (int i = 0; i < 3; ++i)
#pragma unroll
          for (int r = 0; r < 4; ++r)
            xp[i * 4 + r] = (lq < 2)
                ? xg2[pb + (size_t)((w * 3 + i) * 256 + r * 64 + (half * 2 + lq) * 16 + lj)]
                : (unsigned short)0;
      }
#pragma unroll
      for (int i = 0; i < 3; ++i)
        cH[i] = __builtin_amdgcn_mfma_f32_16x16x32_f16(f0, b1[i][0], cH[i], 0, 0, 0);
#pragma unroll
      for (int i = 0; i < 3; ++i)
        cH[i] = __builtin_amdgcn_mfma_f32_16x16x32_f16(f1, b1[i][1], cH[i], 0, 0, 0);
      if (l < 32) {
#pragma unroll
        for (int i = 0; i < 3; ++i) {
          float g0, g1, g2, g3;
          qtrans(cH[i], l, g0, g1, g2, g3);
          const float cc = sigf(g1) * c1s[i] + sigf(g0) * tanh_f(g2);
          c1s[i] = cc;
          const int u = w * 12 + i * 4 + kk;
          hbuf[alt][qn][u] = (_Float16)(sigf(g3) * tanh_f(cc));  // h1(p+1) -> buf[alt]
        }
      }
    }
    if (smth && p >= 1) {  // softmax(p-1): logit_s written in Phase A this p
      const int n = smn;
      const float l0 = logit_s[0][n], l1 = logit_s[1][n], l2 = logit_s[2][n],
                  l3 = logit_s[3][n], l4 = logit_s[4][n];
      const float m = fmaxf(fmaxf(fmaxf(l0, l1), fmaxf(l2, l3)), l4);
      const float e0 = __expf(l0 - m), e1 = __expf(l1 - m), e2 = __expf(l2 - m),
                  e3 = __expf(l3 - m), e4 = __expf(l4 - m);
      const float rs = __builtin_amdgcn_rcpf(e0 + e1 + e2 + e3 + e4);
      prob_s[0][n] = e0 * rs; prob_s[1][n] = e1 * rs; prob_s[2][n] = e2 * rs;
      prob_s[3][n] = e3 * rs; prob_s[4][n] = e4 * rs;
    }
    lds_barrier();
  }
  // ---- epilogue: fc(87) + store(86); softmax(87); store(87) ----
  const int parL = (P_ - 1) & 1;
  if (fcth) {
    float a = fcbr;
#pragma unroll
    for (int uq = 0; uq < 12; ++uq) {
      f32x4 hv = *(const f32x4*)&h2f[parL][fn][uq * 4];
      f32x4 wv = *(const f32x4*)&fcws[fk * 48 + uq * 4];
      a += hv[0] * wv[0] + hv[1] * wv[1] + hv[2] * wv[2] + hv[3] * wv[3];
    }
    logit_s[fk][fn] = a;
  }
  if (stth) {
    out[(((size_t)b * P_ + (P_ - 2)) * 5 + sk) * T_ + t0 + sn] = prob_s[sk][sn];
  }
  lds_barrier();
  if (smth) {
    const int n = smn;
    const float l0 = logit_s[0][n], l1 = logit_s[1][n], l2 = logit_s[2][n],
                l3 = logit_s[3][n], l4 = logit_s[4][n];
    const float m = fmaxf(fmaxf(fmaxf(l0, l1), fmaxf(l2, l3)), l4);
    const float e0 = __expf(l0 - m), e1 = __expf(l1 - m), e2 = __expf(l2 - m),
                e3 = __expf(l3 - m), e4 = __expf(l4 - m);
    const float rs = __builtin_amdgcn_rcpf(e0 + e1 + e2 + e3 + e4);
    prob_s[0][n] = e0 * rs; prob_s[1][n] = e1 * rs; prob_s[2][n] = e2 * rs;
    prob_s[3][n] = e3 * rs; prob_s[4][n] = e4 * rs;
  }
  lds_barrier();
  if (stth) {
    out[(((size_t)b * P_ + (P_ - 1)) * 5 + sk) * T_ + t0 + sn] = prob_s[sk][sn];
  }
}

extern "C" void kernel_launch(void* const* d_in, const int* in_sizes, int n_in,
                              void* d_out, int out_size, void* d_ws, size_t ws_size,
                              hipStream_t stream) {
  const float* pf   = (const float*)d_in[0];
  const float* pc   = (const float*)d_in[1];
  const float* fc1w = (const float*)d_in[2];
  const float* fc1b = (const float*)d_in[3];
  const float* fc2w = (const float*)d_in[4];
  const float* fc2b = (const float*)d_in[5];
  const float* fc3w = (const float*)d_in[6];
  const float* fc3b = (const float*)d_in[7];
  const float* wih1 = (const float*)d_in[8];
  const float* whh1 = (const float*)d_in[9];
  const float* bih1 = (const float*)d_in[10];
  const float* bhh1 = (const float*)d_in[11];
  const float* wih2 = (const float*)d_in[12];
  const float* whh2 = (const float*)d_in[13];
  const float* bih2 = (const float*)d_in[14];
  const float* bhh2 = (const float*)d_in[15];
  const float* fcw  = (const float*)d_in[16];
  const float* fcb  = (const float*)d_in[17];
  float* out = (float*)d_out;

  char* wsp = (char*)d_ws;
  float* ctxg = (float*)wsp;                                     // 1,081,344 B
  const size_t CTXG_BYTES = (size_t)B_ * P_ * G_ * sizeof(float);
  f16x8* wfrag = (f16x8*)(wsp + CTXG_BYTES);                     // 73,728 B
  const size_t WFRAG_BYTES = (size_t)12 * 6 * 64 * 16;
  unsigned short* xg2 = (unsigned short*)(wsp + CTXG_BYTES + WFRAG_BYTES);  // ~138.5 MB

  ctx_kernel<<<22, 64, 0, stream>>>(pc, fc1w, fc1b, fc2w, fc2b, fc3w, fc3b,
                                    wih1, bih1, bhh1, ctxg);
  wfrag_kernel<<<18, 256, 0, stream>>>(wih1, wfrag);
  gemm_mfma<<<B_ * P_ * 2, 256, 0, stream>>>(pf, wfrag, ctxg, xg2);
  scan_mfma<<<N_ / 8, 256, 0, stream>>>(xg2, whh1, wih2, whh2,
                                        bih2, bhh2, fcw, fcb, out);
}

// Round 15
// 449.751 us; speedup vs baseline: 1.0843x; 1.0843x over previous
//
#include <hip/hip_runtime.h>
#include <hip/hip_bf16.h>
#include <cstdint>

#define P_ 88   // pitches (sequence length of the scan)
#define B_ 16   // batch
#define T_ 256  // timesteps (folded into batch N)
#define H_ 188  // per-pitch features
#define G_ 192  // 4*48 gates; also LSTM1 input size (188 feat + 4 ctx)
#define U_ 48   // LSTM units
#define N_ 4096 // B_*T_

typedef __attribute__((ext_vector_type(8))) short bf16x8;
typedef __attribute__((ext_vector_type(8))) _Float16 f16x8;
typedef __attribute__((ext_vector_type(4))) float f32x4;

__device__ __forceinline__ float sigf(float x) {
  return __builtin_amdgcn_rcpf(1.0f + __expf(-x));
}
__device__ __forceinline__ float tanh_f(float x) {
  return 1.0f - 2.0f * __builtin_amdgcn_rcpf(1.0f + __expf(2.0f * x));
}
__device__ __forceinline__ float hs2f(unsigned short s) {
  union { unsigned short u; _Float16 h; } x;
  x.u = s;
  return (float)x.h;
}
__device__ __forceinline__ unsigned short f2hs(float v) {
  union { _Float16 h; unsigned short s; } x;
  x.h = (_Float16)v;
  return x.s;
}

// Relaxed workgroup barrier: waits only on LDS ops (lgkmcnt), NOT vmcnt.
__device__ __forceinline__ void lds_barrier() {
  asm volatile("s_waitcnt lgkmcnt(0)\n\ts_barrier" ::: "memory");
}
// Wave-local LDS fence (producer lanes -> consumer lanes within one wave).
__device__ __forceinline__ void lds_wave_fence() {
  asm volatile("s_waitcnt lgkmcnt(0)" ::: "memory");
}

// ---------------------------------------------------------------------------
// Kernel 1: context MLP -> per-(b,p) gate bias vector
// ---------------------------------------------------------------------------
__global__ void ctx_kernel(const float* __restrict__ pc,
                           const float* __restrict__ fc1w, const float* __restrict__ fc1b,
                           const float* __restrict__ fc2w, const float* __restrict__ fc2b,
                           const float* __restrict__ fc3w, const float* __restrict__ fc3b,
                           const float* __restrict__ wih1,
                           const float* __restrict__ bih1, const float* __restrict__ bhh1,
                           float* __restrict__ ctxg) {
  int bp = blockIdx.x * 64 + threadIdx.x;
  if (bp >= B_ * P_) return;
  float p0 = pc[bp * 3 + 0], p1 = pc[bp * 3 + 1], p2 = pc[bp * 3 + 2];
  float x1[16], x2[16];
#pragma unroll
  for (int jj = 0; jj < 16; ++jj)
    x1[jj] = fmaxf(0.f, fc1w[jj * 3 + 0] * p0 + fc1w[jj * 3 + 1] * p1 + fc1w[jj * 3 + 2] * p2 + fc1b[jj]);
#pragma unroll
  for (int jj = 0; jj < 16; ++jj) {
    float s = fc2b[jj];
#pragma unroll
    for (int i = 0; i < 16; ++i) s += fc2w[jj * 16 + i] * x1[i];
    x2[jj] = fmaxf(0.f, s);
  }
  float ce[4];
#pragma unroll
  for (int jj = 0; jj < 4; ++jj) {
    float s = fc3b[jj];
#pragma unroll
    for (int i = 0; i < 16; ++i) s += fc3w[jj * 16 + i] * x2[i];
    ce[jj] = s;
  }
  float* op = ctxg + (size_t)bp * G_;
  for (int g = 0; g < G_; ++g) {
    const float* wr = wih1 + (size_t)g * G_ + H_;
    op[g] = bih1[g] + bhh1[g] + ce[0] * wr[0] + ce[1] * wr[1] + ce[2] * wr[2] + ce[3] * wr[3];
  }
}

// ---------------------------------------------------------------------------
// Kernel 1b: pack wih1 feature columns into f16 MFMA B-fragment order.
// ---------------------------------------------------------------------------
__global__ __launch_bounds__(256) void wfrag_kernel(const float* __restrict__ wih1,
                                                    f16x8* __restrict__ wfrag) {
  const int idx = blockIdx.x * 256 + threadIdx.x;
  if (idx >= 12 * 6 * 64) return;
  const int l = idx & 63;
  const int kc = (idx >> 6) % 6;
  const int j = idx / 384;
  const int g = j * 16 + (l & 15);
  const int k0 = kc * 32 + (l >> 4) * 8;
  f16x8 v;
#pragma unroll
  for (int e = 0; e < 8; ++e) {
    const int k = k0 + e;
    const float wv = (k < H_) ? wih1[(size_t)g * G_ + k] : 0.f;
    v[e] = (_Float16)wv;
  }
  wfrag[idx] = v;
}

// ---------------------------------------------------------------------------
// Kernel 2: MFMA GEMM (LDS-staged A, LDS-repacked stores). Epilogue scatters
// into the scan's TYPE-INTERLEAVED gate order (verified round 14).
// ---------------------------------------------------------------------------
__global__ __launch_bounds__(256, 3) void gemm_mfma(const float* __restrict__ pf,
                                                    const f16x8* __restrict__ wfrag,
                                                    const float* __restrict__ ctxg,
                                                    unsigned short* __restrict__ xg2) {
  const int bp = blockIdx.x >> 1, tb = blockIdx.x & 1;
  const int p = bp % P_, b = bp / P_;
  const int tid = threadIdx.x;
  const int w = tid >> 6, l = tid & 63;
  const int lj = l & 15, lq = l >> 4;

  __shared__ __align__(16) char ldsraw[49152];
  _Float16(*Ahi)[34] = (_Float16(*)[34])ldsraw;
  _Float16(*Alo)[34] = (_Float16(*)[34])(ldsraw + 8704);

  float cg[12];
#pragma unroll
  for (int jn = 0; jn < 12; ++jn)
    cg[jn] = ctxg[(size_t)bp * G_ + jn * 16 + lj];

  f32x4 acc[2][12];
#pragma unroll
  for (int mt = 0; mt < 2; ++mt)
#pragma unroll
    for (int jn = 0; jn < 12; ++jn)
#pragma unroll
      for (int r = 0; r < 4; ++r) acc[mt][jn][r] = 0.f;

  const float* Ab = pf + (size_t)bp * H_ * T_ + tb * 128;
  const int kl = tid >> 5;
  const int t4 = (tid & 31) * 4;

  for (int kc = 0; kc < 6; ++kc) {
    __syncthreads();
#pragma unroll
    for (int rr = 0; rr < 4; ++rr) {
      const int kk = rr * 8 + kl;
      const int kg = kc * 32 + kk;
      float a0 = 0.f, a1 = 0.f, a2 = 0.f, a3 = 0.f;
      if (kg < H_) {
        const float4 v = *(const float4*)(Ab + (size_t)kg * T_ + t4);
        a0 = v.x; a1 = v.y; a2 = v.z; a3 = v.w;
      }
      const _Float16 h0 = (_Float16)a0, h1 = (_Float16)a1;
      const _Float16 h2 = (_Float16)a2, h3 = (_Float16)a3;
      Ahi[t4 + 0][kk] = h0; Alo[t4 + 0][kk] = (_Float16)(a0 - (float)h0);
      Ahi[t4 + 1][kk] = h1; Alo[t4 + 1][kk] = (_Float16)(a1 - (float)h1);
      Ahi[t4 + 2][kk] = h2; Alo[t4 + 2][kk] = (_Float16)(a2 - (float)h2);
      Ahi[t4 + 3][kk] = h3; Alo[t4 + 3][kk] = (_Float16)(a3 - (float)h3);
    }
    __syncthreads();
    const int trow = w * 32;
    const f16x8 ahi0 = *(const f16x8*)&Ahi[trow + lj][lq * 8];
    const f16x8 ahi1 = *(const f16x8*)&Ahi[trow + 16 + lj][lq * 8];
    const f16x8 alo0 = *(const f16x8*)&Alo[trow + lj][lq * 8];
    const f16x8 alo1 = *(const f16x8*)&Alo[trow + 16 + lj][lq * 8];
#pragma unroll
    for (int jn = 0; jn < 12; ++jn) {
      const f16x8 wf = wfrag[(jn * 6 + kc) * 64 + l];
      acc[0][jn] = __builtin_amdgcn_mfma_f32_16x16x32_f16(ahi0, wf, acc[0][jn], 0, 0, 0);
      acc[1][jn] = __builtin_amdgcn_mfma_f32_16x16x32_f16(ahi1, wf, acc[1][jn], 0, 0, 0);
      acc[0][jn] = __builtin_amdgcn_mfma_f32_16x16x32_f16(alo0, wf, acc[0][jn], 0, 0, 0);
      acc[1][jn] = __builtin_amdgcn_mfma_f32_16x16x32_f16(alo1, wf, acc[1][jn], 0, 0, 0);
    }
  }
  __syncthreads();

  // epilogue: + ctx bias, f16, scatter into type-interleaved scan order.
  unsigned short* Cst = (unsigned short*)ldsraw + w * 6144;
#pragma unroll
  for (int mt = 0; mt < 2; ++mt)
#pragma unroll
    for (int jn = 0; jn < 12; ++jn) {
      const int g = jn * 16 + lj;
      const int t = g / 48;
      const int rem = g - 48 * t;
      const int sw = rem / 12;
      const int ul = rem - 12 * sw;
      const int c = ul * 4 + t;
      const int slot = (sw * 3 + (c >> 4)) * 256 + lq * 16 + (c & 15);
#pragma unroll
      for (int r = 0; r < 4; ++r)
        Cst[mt * 3072 + slot + r * 64] = f2hs(acc[mt][jn][r] + cg[jn]);
    }
  const int nb0 = b * 16 + tb * 8 + w * 2;
  unsigned short* gb = xg2 + ((size_t)p * 256 + nb0) * 3072;
#pragma unroll
  for (int rr = 0; rr < 12; ++rr) {
    const uint4 v = *(const uint4*)(Cst + rr * 512 + l * 8);
    *(uint4*)(gb + rr * 512 + l * 8) = v;
  }
}

// ---------------------------------------------------------------------------
// Kernel 3: MFMA persistent scan, ONE barrier per step.
// Type-interleaved cols (c=i*16+lj -> unit ul=c>>2, type t=c&3, gate
// j = t*48 + w*12 + ul): wave w owns units w*12..w*12+11 with ALL 4 types,
// so gate->activation is wave-local (gs write + lgkmcnt fence, no barrier).
// h parity-buffered f16: step p reads hbuf[p&1] (h1(p), h2(p-1)), writes
// hbuf[(p+1)&1] (h1(p+1), h2(p)). All aux buffers parity-doubled; aux work
// (fc/softmax/store) runs on lanes>=32 in the M-part, barrier-separated.
// ---------------------------------------------------------------------------
__global__ __launch_bounds__(256, 2) void scan_mfma(
    const unsigned short* __restrict__ xg2,
    const float* __restrict__ whh1, const float* __restrict__ wih2,
    const float* __restrict__ whh2, const float* __restrict__ bih2,
    const float* __restrict__ bhh2, const float* __restrict__ fcw,
    const float* __restrict__ fcb, float* __restrict__ out) {
  __shared__ __align__(16) _Float16 hbuf[2][16][120];  // cols 0-47 h1, 48-95 h2
  __shared__ __align__(16) float gs1w[4][8][52];       // wave-local L1 gates
  __shared__ __align__(16) float gs2w[4][8][52];       // wave-local L2 gates
  __shared__ __align__(16) float h2f[2][8][52];        // h2 fp32, parity
  __shared__ __align__(16) float fcws[5 * 48];
  __shared__ float logit_s[2][5][8];
  __shared__ float prob_s[2][5][8];

  const int tid = threadIdx.x;
  const int w = tid >> 6, l = tid & 63;
  const int lj = l & 15, lq = l >> 4;
  const int grp = blockIdx.x >> 1, half = blockIdx.x & 1;
  const int n0 = blockIdx.x * 8;
  const int b = n0 >> 8, t0 = n0 & 255;

  // ---- persistent weight B-fragments, type-interleaved mapping ----
  f16x8 b1[3][2];
  f16x8 b2f[3][3];
  float bias2r[3];
#pragma unroll
  for (int i = 0; i < 3; ++i) {
    const int c = i * 16 + lj;
    const int ul = c >> 2, t = c & 3;
    const int j = t * 48 + w * 12 + ul;
    bias2r[i] = bih2[j] + bhh2[j];
#pragma unroll
    for (int kc = 0; kc < 2; ++kc)
#pragma unroll
      for (int e = 0; e < 8; ++e) {
        const int u = kc * 32 + lq * 8 + e;
        b1[i][kc][e] = (u < U_) ? (_Float16)whh1[j * U_ + u] : (_Float16)0.f;
      }
#pragma unroll
    for (int kc = 0; kc < 3; ++kc)
#pragma unroll
      for (int e = 0; e < 8; ++e) {
        const int k = kc * 32 + lq * 8 + e;
        b2f[i][kc][e] = (k < U_) ? (_Float16)wih2[j * U_ + k]
                                 : (_Float16)whh2[j * U_ + (k - U_)];
      }
  }

  for (int e = tid; e < 2 * 16 * 120 / 2; e += 256) ((unsigned int*)hbuf)[e] = 0u;
  for (int e = tid; e < 2 * 8 * 52; e += 256) ((float*)h2f)[e] = 0.f;
  for (int e = tid; e < 5 * U_; e += 256) fcws[e] = fcw[e];

  // activation task (lanes l<32): row qn, unit u = w*12 + i*4 + kk per tile i
  const int qn = lq * 4 + (l & 3);   // lq in {0,1} for l<32
  const int kk = (l >> 2) & 3;
  float c1s[3] = {0.f, 0.f, 0.f}, c2s[3] = {0.f, 0.f, 0.f};

  // aux roles on lanes >= 32, balanced across all 4 waves
  const bool fcth = (l >= 32 && l < 42);
  const int fi = w * 10 + (l - 32);
  const int fk = (fi >> 3) < 5 ? (fi >> 3) : 0, fn = fi & 7;
  const float fcbr = fcth ? fcb[fk] : 0.f;
  const bool stth = (l >= 42 && l < 52);
  const int ts = w * 10 + (l - 42);
  const int sk = (ts >> 3) < 5 ? (ts >> 3) : 0, sn = ts & 7;
  const bool smth = (l >= 52 && l < 54);
  const int smn = w * 2 + (l - 52);

  // xg prefetch: incremented base pointer + constant offsets (cheap addr math)
  const int lofs = (w * 3) * 256 + (half * 2 + lq) * 16 + lj;
  unsigned short xp[12];
  {
    const unsigned short* x0 = xg2 + (size_t)grp * 3072 + lofs;
#pragma unroll
    for (int i = 0; i < 3; ++i)
#pragma unroll
      for (int r = 0; r < 4; ++r)
        xp[i * 4 + r] = (lq < 2) ? x0[i * 256 + r * 64] : (unsigned short)0;
  }
  const unsigned short* xq = xg2 + (size_t)256 * 3072 + (size_t)grp * 3072 + lofs;
  lds_barrier();

  for (int p = -1; p < P_; ++p) {
    const int rb = p & 1, wb = rb ^ 1;
    // ================= M: MFMAs (read hbuf[rb]) + aux =================
    const _Float16* hr = &hbuf[rb][lj][0];
    const f16x8 f0 = *(const f16x8*)(hr + lq * 8);        // h1 k0-31
    const f16x8 f1 = *(const f16x8*)(hr + 32 + lq * 8);   // h1/h2 k32-63
    if (p >= 0) {  // L2(p): K=96 over [h1(p); h2(p-1)]
      const f16x8 f2 = *(const f16x8*)(hr + 64 + lq * 8);
      f32x4 dH[3];
#pragma unroll
      for (int i = 0; i < 3; ++i) {
        dH[i][0] = bias2r[i]; dH[i][1] = bias2r[i];
        dH[i][2] = bias2r[i]; dH[i][3] = bias2r[i];
      }
#pragma unroll
      for (int i = 0; i < 3; ++i)
        dH[i] = __builtin_amdgcn_mfma_f32_16x16x32_f16(f0, b2f[i][0], dH[i], 0, 0, 0);
#pragma unroll
      for (int i = 0; i < 3; ++i)
        dH[i] = __builtin_amdgcn_mfma_f32_16x16x32_f16(f1, b2f[i][1], dH[i], 0, 0, 0);
#pragma unroll
      for (int i = 0; i < 3; ++i)
        dH[i] = __builtin_amdgcn_mfma_f32_16x16x32_f16(f2, b2f[i][2], dH[i], 0, 0, 0);
      if (lq < 2) {
#pragma unroll
        for (int i = 0; i < 3; ++i)
#pragma unroll
          for (int r = 0; r < 4; ++r)
            gs2w[w][lq * 4 + r][i * 16 + lj] = dH[i][r];
      }
    }
    if (fcth && p >= 1) {  // fc logits of step p-1: h2f[rb] -> logit_s[wb]
      float a = fcbr;
#pragma unroll
      for (int uq = 0; uq < 12; ++uq) {
        f32x4 hv = *(const f32x4*)&h2f[rb][fn][uq * 4];
        f32x4 wv = *(const f32x4*)&fcws[fk * 48 + uq * 4];
        a += hv[0] * wv[0] + hv[1] * wv[1] + hv[2] * wv[2] + hv[3] * wv[3];
      }
      logit_s[wb][fk][fn] = a;
    }
    if (smth && p >= 2) {  // softmax of step p-2: logit_s[rb] -> prob_s[rb]
      const int n = smn;
      const float l0 = logit_s[rb][0][n], l1 = logit_s[rb][1][n],
                  l2 = logit_s[rb][2][n], l3 = logit_s[rb][3][n],
                  l4 = logit_s[rb][4][n];
      const float m = fmaxf(fmaxf(fmaxf(l0, l1), fmaxf(l2, l3)), l4);
      const float e0 = __expf(l0 - m), e1 = __expf(l1 - m), e2 = __expf(l2 - m),
                  e3 = __expf(l3 - m), e4 = __expf(l4 - m);
      const float rs = __builtin_amdgcn_rcpf(e0 + e1 + e2 + e3 + e4);
      prob_s[rb][0][n] = e0 * rs; prob_s[rb][1][n] = e1 * rs;
      prob_s[rb][2][n] = e2 * rs; prob_s[rb][3][n] = e3 * rs;
      prob_s[rb][4][n] = e4 * rs;
    }
    if (stth && p >= 3) {  // store of step p-3: prob_s[wb]
      out[(((size_t)b * P_ + (p - 3)) * 5 + sk) * T_ + t0 + sn] = prob_s[wb][sk][sn];
    }
    __builtin_amdgcn_sched_barrier(0);
    if (p < P_ - 1) {  // L1(p+1): C = xg(p+1), K=48 (pad: b1 rows>=48 zero)
      f32x4 cH[3];
#pragma unroll
      for (int i = 0; i < 3; ++i)
#pragma unroll
        for (int r = 0; r < 4; ++r) cH[i][r] = hs2f(xp[i * 4 + r]);
      if (p < P_ - 2) {  // prefetch slice p+2; stays in flight over barrier
#pragma unroll
        for (int i = 0; i < 3; ++i)
#pragma unroll
          for (int r = 0; r < 4; ++r)
            xp[i * 4 + r] = (lq < 2) ? xq[i * 256 + r * 64] : (unsigned short)0;
        xq += (size_t)256 * 3072;
      }
#pragma unroll
      for (int i = 0; i < 3; ++i)
        cH[i] = __builtin_amdgcn_mfma_f32_16x16x32_f16(f0, b1[i][0], cH[i], 0, 0, 0);
#pragma unroll
      for (int i = 0; i < 3; ++i)
        cH[i] = __builtin_amdgcn_mfma_f32_16x16x32_f16(f1, b1[i][1], cH[i], 0, 0, 0);
      if (lq < 2) {
#pragma unroll
        for (int i = 0; i < 3; ++i)
#pragma unroll
          for (int r = 0; r < 4; ++r)
            gs1w[w][lq * 4 + r][i * 16 + lj] = cH[i][r];
      }
    }
    lds_wave_fence();  // gs writes visible to this wave's own act lanes
    // ================= V: activations (write hbuf[wb]) =================
    if (l < 32) {
      if (p >= 0) {  // act2(p) -> h2(p) @ hbuf[wb], h2f[wb]
#pragma unroll
        for (int i = 0; i < 3; ++i) {
          const f32x4 g = *(const f32x4*)&gs2w[w][qn][(i * 4 + kk) * 4];
          const float cc = sigf(g[1]) * c2s[i] + sigf(g[0]) * tanh_f(g[2]);
          c2s[i] = cc;
          const float h = sigf(g[3]) * tanh_f(cc);
          const int u = w * 12 + i * 4 + kk;
          hbuf[wb][qn][48 + u] = (_Float16)h;
          h2f[wb][qn][u] = h;
        }
      }
      if (p < P_ - 1) {  // act1(p+1) -> h1(p+1) @ hbuf[wb]
#pragma unroll
        for (int i = 0; i < 3; ++i) {
          const f32x4 g = *(const f32x4*)&gs1w[w][qn][(i * 4 + kk) * 4];
          const float cc = sigf(g[1]) * c1s[i] + sigf(g[0]) * tanh_f(g[2]);
          c1s[i] = cc;
          const int u = w * 12 + i * 4 + kk;
          hbuf[wb][qn][u] = (_Float16)(sigf(g[3]) * tanh_f(cc));
        }
      }
    }
    lds_barrier();
  }
  // ---- epilogue: virtual p=88,89,90 aux flushes ----
  // E1 (p=88: rb=0, wb=1): fc(87), sm(86), st(85)
  if (fcth) {
    float a = fcbr;
#pragma unroll
    for (int uq = 0; uq < 12; ++uq) {
      f32x4 hv = *(const f32x4*)&h2f[0][fn][uq * 4];
      f32x4 wv = *(const f32x4*)&fcws[fk * 48 + uq * 4];
      a += hv[0] * wv[0] + hv[1] * wv[1] + hv[2] * wv[2] + hv[3] * wv[3];
    }
    logit_s[1][fk][fn] = a;
  }
  if (smth) {
    const int n = smn;
    const float l0 = logit_s[0][0][n], l1 = logit_s[0][1][n], l2 = logit_s[0][2][n],
                l3 = logit_s[0][3][n], l4 = logit_s[0][4][n];
    const float m = fmaxf(fmaxf(fmaxf(l0, l1), fmaxf(l2, l3)), l4);
    const float e0 = __expf(l0 - m), e1 = __expf(l1 - m), e2 = __expf(l2 - m),
                e3 = __expf(l3 - m), e4 = __expf(l4 - m);
    const float rs = __builtin_amdgcn_rcpf(e0 + e1 + e2 + e3 + e4);
    prob_s[0][0][n] = e0 * rs; prob_s[0][1][n] = e1 * rs; prob_s[0][2][n] = e2 * rs;
    prob_s[0][3][n] = e3 * rs; prob_s[0][4][n] = e4 * rs;
  }
  if (stth) {
    out[(((size_t)b * P_ + 85) * 5 + sk) * T_ + t0 + sn] = prob_s[1][sk][sn];
  }
  lds_barrier();
  // E2 (p=89: rb=1, wb=0): sm(87), st(86)
  if (smth) {
    const int n = smn;
    const float l0 = logit_s[1][0][n], l1 = logit_s[1][1][n], l2 = logit_s[1][2][n],
                l3 = logit_s[1][3][n], l4 = logit_s[1][4][n];
    const float m = fmaxf(fmaxf(fmaxf(l0, l1), fmaxf(l2, l3)), l4);
    const float e0 = __expf(l0 - m), e1 = __expf(l1 - m), e2 = __expf(l2 - m),
                e3 = __expf(l3 - m), e4 = __expf(l4 - m);
    const float rs = __builtin_amdgcn_rcpf(e0 + e1 + e2 + e3 + e4);
    prob_s[1][0][n] = e0 * rs; prob_s[1][1][n] = e1 * rs; prob_s[1][2][n] = e2 * rs;
    prob_s[1][3][n] = e3 * rs; prob_s[1][4][n] = e4 * rs;
  }
  if (stth) {
    out[(((size_t)b * P_ + 86) * 5 + sk) * T_ + t0 + sn] = prob_s[0][sk][sn];
  }
  lds_barrier();
  // E3 (p=90): st(87)
  if (stth) {
    out[(((size_t)b * P_ + 87) * 5 + sk) * T_ + t0 + sn] = prob_s[1][sk][sn];
  }
}

extern "C" void kernel_launch(void* const* d_in, const int* in_sizes, int n_in,
                              void* d_out, int out_size, void* d_ws, size_t ws_size,
                              hipStream_t stream) {
  const float* pf   = (const float*)d_in[0];
  const float* pc   = (const float*)d_in[1];
  const float* fc1w = (const float*)d_in[2];
  const float* fc1b = (const float*)d_in[3];
  const float* fc2w = (const float*)d_in[4];
  const float* fc2b = (const float*)d_in[5];
  const float* fc3w = (const float*)d_in[6];
  const float* fc3b = (const float*)d_in[7];
  const float* wih1 = (const float*)d_in[8];
  const float* whh1 = (const float*)d_in[9];
  const float* bih1 = (const float*)d_in[10];
  const float* bhh1 = (const float*)d_in[11];
  const float* wih2 = (const float*)d_in[12];
  const float* whh2 = (const float*)d_in[13];
  const float* bih2 = (const float*)d_in[14];
  const float* bhh2 = (const float*)d_in[15];
  const float* fcw  = (const float*)d_in[16];
  const float* fcb  = (const float*)d_in[17];
  float* out = (float*)d_out;

  char* wsp = (char*)d_ws;
  float* ctxg = (float*)wsp;                                     // 1,081,344 B
  const size_t CTXG_BYTES = (size_t)B_ * P_ * G_ * sizeof(float);
  f16x8* wfrag = (f16x8*)(wsp + CTXG_BYTES);                     // 73,728 B
  const size_t WFRAG_BYTES = (size_t)12 * 6 * 64 * 16;
  unsigned short* xg2 = (unsigned short*)(wsp + CTXG_BYTES + WFRAG_BYTES);  // ~138.5 MB

  ctx_kernel<<<22, 64, 0, stream>>>(pc, fc1w, fc1b, fc2w, fc2b, fc3w, fc3b,
                                    wih1, bih1, bhh1, ctxg);
  wfrag_kernel<<<18, 256, 0, stream>>>(wih1, wfrag);
  gemm_mfma<<<B_ * P_ * 2, 256, 0, stream>>>(pf, wfrag, ctxg, xg2);
  scan_mfma<<<N_ / 8, 256, 0, stream>>>(xg2, whh1, wih2, whh2,
                                        bih2, bhh2, fcw, fcb, out);
}

// Round 16
// 431.968 us; speedup vs baseline: 1.1289x; 1.0412x over previous
//
#include <hip/hip_runtime.h>
#include <hip/hip_bf16.h>
#include <cstdint>

#define P_ 88   // pitches (sequence length of the scan)
#define B_ 16   // batch
#define T_ 256  // timesteps (folded into batch N)
#define H_ 188  // per-pitch features
#define G_ 192  // 4*48 gates; also LSTM1 input size (188 feat + 4 ctx)
#define U_ 48   // LSTM units
#define N_ 4096 // B_*T_

typedef __attribute__((ext_vector_type(8))) _Float16 f16x8;
typedef __attribute__((ext_vector_type(4))) float f32x4;

__device__ __forceinline__ float sigf(float x) {
  return __builtin_amdgcn_rcpf(1.0f + __expf(-x));
}
__device__ __forceinline__ float tanh_f(float x) {
  return 1.0f - 2.0f * __builtin_amdgcn_rcpf(1.0f + __expf(2.0f * x));
}

// Relaxed workgroup barrier: waits only on LDS ops (lgkmcnt), NOT vmcnt.
__device__ __forceinline__ void lds_barrier() {
  asm volatile("s_waitcnt lgkmcnt(0)\n\ts_barrier" ::: "memory");
}

// ---------------------------------------------------------------------------
// Kernel 1: context MLP -> per-(b,p) gate bias vector (incl. bih1+bhh1).
// ---------------------------------------------------------------------------
__global__ void ctx_kernel(const float* __restrict__ pc,
                           const float* __restrict__ fc1w, const float* __restrict__ fc1b,
                           const float* __restrict__ fc2w, const float* __restrict__ fc2b,
                           const float* __restrict__ fc3w, const float* __restrict__ fc3b,
                           const float* __restrict__ wih1,
                           const float* __restrict__ bih1, const float* __restrict__ bhh1,
                           float* __restrict__ ctxg) {
  int bp = blockIdx.x * 64 + threadIdx.x;
  if (bp >= B_ * P_) return;
  float p0 = pc[bp * 3 + 0], p1 = pc[bp * 3 + 1], p2 = pc[bp * 3 + 2];
  float x1[16], x2[16];
#pragma unroll
  for (int jj = 0; jj < 16; ++jj)
    x1[jj] = fmaxf(0.f, fc1w[jj * 3 + 0] * p0 + fc1w[jj * 3 + 1] * p1 + fc1w[jj * 3 + 2] * p2 + fc1b[jj]);
#pragma unroll
  for (int jj = 0; jj < 16; ++jj) {
    float s = fc2b[jj];
#pragma unroll
    for (int i = 0; i < 16; ++i) s += fc2w[jj * 16 + i] * x1[i];
    x2[jj] = fmaxf(0.f, s);
  }
  float ce[4];
#pragma unroll
  for (int jj = 0; jj < 4; ++jj) {
    float s = fc3b[jj];
#pragma unroll
    for (int i = 0; i < 16; ++i) s += fc3w[jj * 16 + i] * x2[i];
    ce[jj] = s;
  }
  float* op = ctxg + (size_t)bp * G_;
  for (int g = 0; g < G_; ++g) {
    const float* wr = wih1 + (size_t)g * G_ + H_;
    op[g] = bih1[g] + bhh1[g] + ce[0] * wr[0] + ce[1] * wr[1] + ce[2] * wr[2] + ce[3] * wr[3];
  }
}

// ---------------------------------------------------------------------------
// Kernel 2: FUSED scan + input GEMM. 512 blocks (2/CU) x 256 threads, NB=8.
// Structure = round-13's proven 2-phase scan (M: L2(p)+L1(p+1)+aux; V: acts)
// PLUS fused input GEMM: during M(p), compute xg(p+2) = pf(p+2)·wih1^T +
// ctxg(p+2) via MFMA from LDS-staged hi/lo-f16 pf, and stage pf(p+3).
// xg stays in f32 registers (inGEMM C-fragment == L1 C-init fragment).
// Kills the separate GEMM kernel and all xg global traffic.
// ---------------------------------------------------------------------------
__global__ __launch_bounds__(256, 2) void scan_fused(
    const float* __restrict__ pf, const float* __restrict__ ctxg,
    const float* __restrict__ wih1, const float* __restrict__ whh1,
    const float* __restrict__ wih2, const float* __restrict__ whh2,
    const float* __restrict__ bih2, const float* __restrict__ bhh2,
    const float* __restrict__ fcw, const float* __restrict__ fcb,
    float* __restrict__ out) {
  __shared__ __align__(16) _Float16 h12[16][104];  // cols 0-47 h1, 48-95 h2
  __shared__ __align__(16) float gs1[8][196];      // L1 gate staging
  __shared__ __align__(16) float gs2[8][196];      // L2 gate staging
  __shared__ __align__(16) float h2f[8][52];       // h2 fp32 for fc_states
  __shared__ __align__(16) float fcws[5 * 48];
  __shared__ float logit_s[5][8];
  __shared__ float prob_s[5][8];
  __shared__ __align__(16) _Float16 pfhi[2][8][200];  // staged pf hi, [t][h] pad200
  __shared__ __align__(16) _Float16 pflo[2][8][200];  // staged pf lo

  const int tid = threadIdx.x;
  const int w = tid >> 6, l = tid & 63;
  const int lj = l & 15, lq = l >> 4;
  const int n0 = blockIdx.x * 8;
  const int b = n0 >> 8, t0 = n0 & 255;

  // ---- persistent weight B-fragments (f16): recurrent + input GEMM ----
  f16x8 b1[3][2];    // whh1 cols, K=48 pad 64
  f16x8 b2f[3][3];   // [wih2; whh2] cols, K=96
  f16x8 wf[3][6];    // wih1 feature cols, K=188 pad 192
  float bias2r[3];
#pragma unroll
  for (int i = 0; i < 3; ++i) {
    const int j = w * 48 + i * 16 + lj;
    bias2r[i] = bih2[j] + bhh2[j];
#pragma unroll
    for (int kc = 0; kc < 2; ++kc)
#pragma unroll
      for (int e = 0; e < 8; ++e) {
        const int u = kc * 32 + lq * 8 + e;
        b1[i][kc][e] = (u < U_) ? (_Float16)whh1[j * U_ + u] : (_Float16)0.f;
      }
#pragma unroll
    for (int kc = 0; kc < 3; ++kc)
#pragma unroll
      for (int e = 0; e < 8; ++e) {
        const int k = kc * 32 + lq * 8 + e;
        b2f[i][kc][e] = (k < U_) ? (_Float16)wih2[j * U_ + k]
                                 : (_Float16)whh2[j * U_ + (k - U_)];
      }
#pragma unroll
    for (int kc = 0; kc < 6; ++kc)
#pragma unroll
      for (int e = 0; e < 8; ++e) {
        const int k = kc * 32 + lq * 8 + e;
        wf[i][kc][e] = (k < H_) ? (_Float16)wih1[(size_t)j * G_ + k] : (_Float16)0.f;
      }
  }

  // ---- zero LDS state, load fc weights ----
  for (int e = tid; e < 16 * 104 / 2; e += 256) ((unsigned*)h12)[e] = 0u;
  for (int e = tid; e < 1600; e += 256) {  // 2*8*200 halves = 1600 uints each
    ((unsigned*)pfhi)[e] = 0u;
    ((unsigned*)pflo)[e] = 0u;
  }
  for (int e = tid; e < 5 * U_; e += 256) fcws[e] = fcw[e];
  lds_barrier();  // zeros complete before staging writes

  // activation tasks: 384 = 8n x 48u per layer; slot0 = tid, slot1 = 256+tid
  const int tn0 = tid / U_, tu0 = tid % U_;
  const int tn1 = (256 + tid) / U_, tu1 = (256 + tid) % U_;
  const bool has2 = (tid < 128);
  float c1s[2] = {0.f, 0.f}, c2s[2] = {0.f, 0.f};

  // aux roles (r13): fc tid 0-39, store 96-135, softmax 192-199
  const bool fcth = tid < 40;
  const int fk = tid >> 3, fn = tid & 7;
  const float fcbr = fcth ? fcb[fk] : 0.f;
  const bool stth = tid >= 96 && tid < 136;
  const int sk = (tid - 96) >> 3, sn = (tid - 96) & 7;
  const bool smth = tid >= 192 && tid < 200;
  const int smn = tid - 192;

  // ---- pf staging coords: thread covers (h = tid/8 + 32*it, t = t0 + tid%8) ----
  const int sh = tid >> 3, stl = tid & 7;
  const float* pfb = pf + (size_t)b * P_ * H_ * T_ + (size_t)sh * T_ + t0 + stl;

  // prologue: stage pf(0) -> buf0, pf(1) -> buf1
#pragma unroll
  for (int it = 0; it < 6; ++it) {
    const int h = sh + it * 32;
    if (h < H_) {
      const float v0 = pfb[(size_t)it * 32 * T_];
      const float v1 = pfb[(size_t)H_ * T_ + (size_t)it * 32 * T_];
      const _Float16 h0 = (_Float16)v0, h1 = (_Float16)v1;
      pfhi[0][stl][h] = h0; pflo[0][stl][h] = (_Float16)(v0 - (float)h0);
      pfhi[1][stl][h] = h1; pflo[1][stl][h] = (_Float16)(v1 - (float)h1);
    }
  }
  lds_barrier();

  // ctx-bias registers: cg for xg(0) now, cgN = cg(1) for first in-loop prod
  const float* cgbase = ctxg + (size_t)b * P_ * G_ + w * 48 + lj;
  float cgN[3];
  f32x4 xgC[3];
#pragma unroll
  for (int i = 0; i < 3; ++i) {
    const float c0 = cgbase[i * 16];
    xgC[i][0] = c0; xgC[i][1] = c0; xgC[i][2] = c0; xgC[i][3] = c0;
    cgN[i] = cgbase[G_ + i * 16];
  }
  const float* cgp = cgbase + 2 * G_;

#define INGEMM(ACC, RB)                                                        \
  {                                                                            \
    _Pragma("unroll") for (int c = 0; c < 6; ++c) {                            \
      const f16x8 ah = *(const f16x8*)&pfhi[RB][lj & 7][c * 32 + lq * 8];      \
      const f16x8 al = *(const f16x8*)&pflo[RB][lj & 7][c * 32 + lq * 8];      \
      ACC[0] = __builtin_amdgcn_mfma_f32_16x16x32_f16(ah, wf[0][c], ACC[0], 0, 0, 0); \
      ACC[1] = __builtin_amdgcn_mfma_f32_16x16x32_f16(ah, wf[1][c], ACC[1], 0, 0, 0); \
      ACC[2] = __builtin_amdgcn_mfma_f32_16x16x32_f16(ah, wf[2][c], ACC[2], 0, 0, 0); \
      ACC[0] = __builtin_amdgcn_mfma_f32_16x16x32_f16(al, wf[0][c], ACC[0], 0, 0, 0); \
      ACC[1] = __builtin_amdgcn_mfma_f32_16x16x32_f16(al, wf[1][c], ACC[1], 0, 0, 0); \
      ACC[2] = __builtin_amdgcn_mfma_f32_16x16x32_f16(al, wf[2][c], ACC[2], 0, 0, 0); \
    }                                                                          \
  }

  // prologue inGEMM: xgC = xg(0) from buf0
  INGEMM(xgC, 0);
  lds_barrier();  // all waves done reading buf0 before M(-1) re-stages it

  const float* pfstage = pfb + (size_t)2 * H_ * T_;  // pf(2) slice

  for (int p = -1; p < P_; ++p) {
    const bool doL2 = (p >= 0), doL1 = (p < P_ - 1);
    const bool doProd = (p <= 85), doStage = (p <= 84);
    const int prb = p & 1;          // inGEMM reads pf(p+2) from buf[p&1]
    const int pwb = prb ^ 1;        // stage pf(p+3) into the other buffer

    // ---- issue pf(p+3) global loads first (latency hides under MFMAs) ----
    float pv[6];
    if (doStage) {
#pragma unroll
      for (int it = 0; it < 6; ++it)
        pv[it] = (sh + it * 32 < H_) ? pfstage[(size_t)it * 32 * T_] : 0.f;
    }

    // ================= M: MFMA phase =================
    const _Float16* hr = &h12[lj][0];
    const f16x8 f0 = *(const f16x8*)(hr + lq * 8);        // h1 k0-31
    const f16x8 f1 = *(const f16x8*)(hr + 32 + lq * 8);   // h1/h2 k32-63
    if (doL2) {  // L2(p): K=96 over [h1(p); h2(p-1)]
      const f16x8 f2 = *(const f16x8*)(hr + 64 + lq * 8);
      f32x4 dH[3];
#pragma unroll
      for (int i = 0; i < 3; ++i) {
        dH[i][0] = bias2r[i]; dH[i][1] = bias2r[i];
        dH[i][2] = bias2r[i]; dH[i][3] = bias2r[i];
      }
#pragma unroll
      for (int i = 0; i < 3; ++i)
        dH[i] = __builtin_amdgcn_mfma_f32_16x16x32_f16(f0, b2f[i][0], dH[i], 0, 0, 0);
#pragma unroll
      for (int i = 0; i < 3; ++i)
        dH[i] = __builtin_amdgcn_mfma_f32_16x16x32_f16(f1, b2f[i][1], dH[i], 0, 0, 0);
#pragma unroll
      for (int i = 0; i < 3; ++i)
        dH[i] = __builtin_amdgcn_mfma_f32_16x16x32_f16(f2, b2f[i][2], dH[i], 0, 0, 0);
      if (lq < 2) {
#pragma unroll
        for (int i = 0; i < 3; ++i)
#pragma unroll
          for (int r = 0; r < 4; ++r)
            gs2[lq * 4 + r][w * 48 + i * 16 + lj] = dH[i][r];
      }
    }
    if (fcth && p >= 1) {  // fc logits of step p-1
      float a = fcbr;
#pragma unroll
      for (int uq = 0; uq < 12; ++uq) {
        f32x4 hv = *(const f32x4*)&h2f[fn][uq * 4];
        f32x4 wv = *(const f32x4*)&fcws[fk * 48 + uq * 4];
        a += hv[0] * wv[0] + hv[1] * wv[1] + hv[2] * wv[2] + hv[3] * wv[3];
      }
      logit_s[fk][fn] = a;
    }
    if (stth && p >= 2) {  // store probs of step p-2
      out[(((size_t)b * P_ + (p - 2)) * 5 + sk) * T_ + t0 + sn] = prob_s[sk][sn];
    }
    __builtin_amdgcn_sched_barrier(0);
    if (doL1) {  // L1(p+1): C = xgC (f32 xg(p+1), ctx bias included), K=48
      f32x4 cH[3];
#pragma unroll
      for (int i = 0; i < 3; ++i)
        cH[i] = __builtin_amdgcn_mfma_f32_16x16x32_f16(f0, b1[i][0], xgC[i], 0, 0, 0);
#pragma unroll
      for (int i = 0; i < 3; ++i)
        cH[i] = __builtin_amdgcn_mfma_f32_16x16x32_f16(f1, b1[i][1], cH[i], 0, 0, 0);
      if (lq < 2) {
#pragma unroll
        for (int i = 0; i < 3; ++i)
#pragma unroll
          for (int r = 0; r < 4; ++r)
            gs1[lq * 4 + r][w * 48 + i * 16 + lj] = cH[i][r];
      }
    }
    if (doProd) {  // inGEMM: xg(p+2) = ctx(p+2) + pf(p+2)·W (hi+lo terms)
      f32x4 xgP[3];
#pragma unroll
      for (int i = 0; i < 3; ++i) {
        xgP[i][0] = cgN[i]; xgP[i][1] = cgN[i];
        xgP[i][2] = cgN[i]; xgP[i][3] = cgN[i];
      }
      INGEMM(xgP, prb);
      if (doStage) {  // reload cgN = ctx(p+3)
#pragma unroll
        for (int i = 0; i < 3; ++i) cgN[i] = cgp[i * 16];
        cgp += G_;
      }
#pragma unroll
      for (int i = 0; i < 3; ++i) xgC[i] = xgP[i];
    }
    if (doStage) {  // convert + LDS-write pf(p+3) into buf[pwb]
#pragma unroll
      for (int it = 0; it < 6; ++it) {
        const int h = sh + it * 32;
        if (h < H_) {
          const _Float16 hi = (_Float16)pv[it];
          pfhi[pwb][stl][h] = hi;
          pflo[pwb][stl][h] = (_Float16)(pv[it] - (float)hi);
        }
      }
      pfstage += (size_t)H_ * T_;
    }
    lds_barrier();
    // ================= V: activation phase =================
    if (doL2) {  // act2(p) -> h2(p), h2f(p)
      {
        const int n = tn0, u = tu0;
        const float ig = gs2[n][u], fg = gs2[n][48 + u];
        const float gg = gs2[n][96 + u], og = gs2[n][144 + u];
        const float cc = sigf(fg) * c2s[0] + sigf(ig) * tanh_f(gg);
        c2s[0] = cc;
        const float h = sigf(og) * tanh_f(cc);
        h12[n][48 + u] = (_Float16)h;
        h2f[n][u] = h;
      }
      if (has2) {
        const int n = tn1, u = tu1;
        const float ig = gs2[n][u], fg = gs2[n][48 + u];
        const float gg = gs2[n][96 + u], og = gs2[n][144 + u];
        const float cc = sigf(fg) * c2s[1] + sigf(ig) * tanh_f(gg);
        c2s[1] = cc;
        const float h = sigf(og) * tanh_f(cc);
        h12[n][48 + u] = (_Float16)h;
        h2f[n][u] = h;
      }
    }
    if (doL1) {  // act1(p+1) -> h1(p+1)
      {
        const int n = tn0, u = tu0;
        const float ig = gs1[n][u], fg = gs1[n][48 + u];
        const float gg = gs1[n][96 + u], og = gs1[n][144 + u];
        const float cc = sigf(fg) * c1s[0] + sigf(ig) * tanh_f(gg);
        c1s[0] = cc;
        h12[n][u] = (_Float16)(sigf(og) * tanh_f(cc));
      }
      if (has2) {
        const int n = tn1, u = tu1;
        const float ig = gs1[n][u], fg = gs1[n][48 + u];
        const float gg = gs1[n][96 + u], og = gs1[n][144 + u];
        const float cc = sigf(fg) * c1s[1] + sigf(ig) * tanh_f(gg);
        c1s[1] = cc;
        h12[n][u] = (_Float16)(sigf(og) * tanh_f(cc));
      }
    }
    if (smth && p >= 1) {  // softmax of step p-1 (logits from M(p))
      const int n = smn;
      const float l0 = logit_s[0][n], l1 = logit_s[1][n], l2 = logit_s[2][n],
                  l3 = logit_s[3][n], l4 = logit_s[4][n];
      const float m = fmaxf(fmaxf(fmaxf(l0, l1), fmaxf(l2, l3)), l4);
      const float e0 = __expf(l0 - m), e1 = __expf(l1 - m), e2 = __expf(l2 - m),
                  e3 = __expf(l3 - m), e4 = __expf(l4 - m);
      const float rs = __builtin_amdgcn_rcpf(e0 + e1 + e2 + e3 + e4);
      prob_s[0][n] = e0 * rs; prob_s[1][n] = e1 * rs; prob_s[2][n] = e2 * rs;
      prob_s[3][n] = e3 * rs; prob_s[4][n] = e4 * rs;
    }
    lds_barrier();
  }
  // ---- epilogue: fc(87) + store(86); softmax(87); store(87) ----
  if (fcth) {
    float a = fcbr;
#pragma unroll
    for (int uq = 0; uq < 12; ++uq) {
      f32x4 hv = *(const f32x4*)&h2f[fn][uq * 4];
      f32x4 wv = *(const f32x4*)&fcws[fk * 48 + uq * 4];
      a += hv[0] * wv[0] + hv[1] * wv[1] + hv[2] * wv[2] + hv[3] * wv[3];
    }
    logit_s[fk][fn] = a;
  }
  if (stth) {
    out[(((size_t)b * P_ + (P_ - 2)) * 5 + sk) * T_ + t0 + sn] = prob_s[sk][sn];
  }
  lds_barrier();
  if (smth) {
    const int n = smn;
    const float l0 = logit_s[0][n], l1 = logit_s[1][n], l2 = logit_s[2][n],
                l3 = logit_s[3][n], l4 = logit_s[4][n];
    const float m = fmaxf(fmaxf(fmaxf(l0, l1), fmaxf(l2, l3)), l4);
    const float e0 = __expf(l0 - m), e1 = __expf(l1 - m), e2 = __expf(l2 - m),
                e3 = __expf(l3 - m), e4 = __expf(l4 - m);
    const float rs = __builtin_amdgcn_rcpf(e0 + e1 + e2 + e3 + e4);
    prob_s[0][n] = e0 * rs; prob_s[1][n] = e1 * rs; prob_s[2][n] = e2 * rs;
    prob_s[3][n] = e3 * rs; prob_s[4][n] = e4 * rs;
  }
  lds_barrier();
  if (stth) {
    out[(((size_t)b * P_ + (P_ - 1)) * 5 + sk) * T_ + t0 + sn] = prob_s[sk][sn];
  }
}

extern "C" void kernel_launch(void* const* d_in, const int* in_sizes, int n_in,
                              void* d_out, int out_size, void* d_ws, size_t ws_size,
                              hipStream_t stream) {
  const float* pf   = (const float*)d_in[0];
  const float* pc   = (const float*)d_in[1];
  const float* fc1w = (const float*)d_in[2];
  const float* fc1b = (const float*)d_in[3];
  const float* fc2w = (const float*)d_in[4];
  const float* fc2b = (const float*)d_in[5];
  const float* fc3w = (const float*)d_in[6];
  const float* fc3b = (const float*)d_in[7];
  const float* wih1 = (const float*)d_in[8];
  const float* whh1 = (const float*)d_in[9];
  const float* bih1 = (const float*)d_in[10];
  const float* bhh1 = (const float*)d_in[11];
  const float* wih2 = (const float*)d_in[12];
  const float* whh2 = (const float*)d_in[13];
  const float* bih2 = (const float*)d_in[14];
  const float* bhh2 = (const float*)d_in[15];
  const float* fcw  = (const float*)d_in[16];
  const float* fcb  = (const float*)d_in[17];
  float* out = (float*)d_out;

  float* ctxg = (float*)d_ws;  // (B*P) x 192 fp32 = ~1.08 MB

  ctx_kernel<<<22, 64, 0, stream>>>(pc, fc1w, fc1b, fc2w, fc2b, fc3w, fc3b,
                                    wih1, bih1, bhh1, ctxg);
  scan_fused<<<N_ / 8, 256, 0, stream>>>(pf, ctxg, wih1, whh1, wih2, whh2,
                                         bih2, bhh2, fcw, fcb, out);
}

// Round 17
// 392.335 us; speedup vs baseline: 1.2430x; 1.1010x over previous
//
#include <hip/hip_runtime.h>
#include <hip/hip_bf16.h>
#include <cstdint>

#define P_ 88   // pitches (sequence length of the scan)
#define B_ 16   // batch
#define T_ 256  // timesteps (folded into batch N)
#define H_ 188  // per-pitch features
#define G_ 192  // 4*48 gates; also LSTM1 input size (188 feat + 4 ctx)
#define U_ 48   // LSTM units
#define N_ 4096 // B_*T_

typedef __attribute__((ext_vector_type(8))) _Float16 f16x8;
typedef __attribute__((ext_vector_type(4))) float f32x4;

__device__ __forceinline__ float sigf(float x) {
  return __builtin_amdgcn_rcpf(1.0f + __expf(-x));
}
__device__ __forceinline__ float tanh_f(float x) {
  return 1.0f - 2.0f * __builtin_amdgcn_rcpf(1.0f + __expf(2.0f * x));
}

// Relaxed workgroup barrier: waits only on LDS ops (lgkmcnt), NOT vmcnt.
__device__ __forceinline__ void lds_barrier() {
  asm volatile("s_waitcnt lgkmcnt(0)\n\ts_barrier" ::: "memory");
}

// ---------------------------------------------------------------------------
// Kernel 1: context MLP -> per-(b,p) gate bias vector (incl. bih1+bhh1).
// ---------------------------------------------------------------------------
__global__ void ctx_kernel(const float* __restrict__ pc,
                           const float* __restrict__ fc1w, const float* __restrict__ fc1b,
                           const float* __restrict__ fc2w, const float* __restrict__ fc2b,
                           const float* __restrict__ fc3w, const float* __restrict__ fc3b,
                           const float* __restrict__ wih1,
                           const float* __restrict__ bih1, const float* __restrict__ bhh1,
                           float* __restrict__ ctxg) {
  int bp = blockIdx.x * 64 + threadIdx.x;
  if (bp >= B_ * P_) return;
  float p0 = pc[bp * 3 + 0], p1 = pc[bp * 3 + 1], p2 = pc[bp * 3 + 2];
  float x1[16], x2[16];
#pragma unroll
  for (int jj = 0; jj < 16; ++jj)
    x1[jj] = fmaxf(0.f, fc1w[jj * 3 + 0] * p0 + fc1w[jj * 3 + 1] * p1 + fc1w[jj * 3 + 2] * p2 + fc1b[jj]);
#pragma unroll
  for (int jj = 0; jj < 16; ++jj) {
    float s = fc2b[jj];
#pragma unroll
    for (int i = 0; i < 16; ++i) s += fc2w[jj * 16 + i] * x1[i];
    x2[jj] = fmaxf(0.f, s);
  }
  float ce[4];
#pragma unroll
  for (int jj = 0; jj < 4; ++jj) {
    float s = fc3b[jj];
#pragma unroll
    for (int i = 0; i < 16; ++i) s += fc3w[jj * 16 + i] * x2[i];
    ce[jj] = s;
  }
  float* op = ctxg + (size_t)bp * G_;
  for (int g = 0; g < G_; ++g) {
    const float* wr = wih1 + (size_t)g * G_ + H_;
    op[g] = bih1[g] + bhh1[g] + ce[0] * wr[0] + ce[1] * wr[1] + ce[2] * wr[2] + ce[3] * wr[3];
  }
}

// ---------------------------------------------------------------------------
// Kernel 2: FUSED scan + input GEMM (round 16) + XCD-aware block swizzle:
// all 32 blocks sharing a batch index b land on ONE XCD, so their scattered
// pf reads (32B-of-1KB-row per block) dedupe in that XCD's L2.
// ---------------------------------------------------------------------------
__global__ __launch_bounds__(256, 2) void scan_fused(
    const float* __restrict__ pf, const float* __restrict__ ctxg,
    const float* __restrict__ wih1, const float* __restrict__ whh1,
    const float* __restrict__ wih2, const float* __restrict__ whh2,
    const float* __restrict__ bih2, const float* __restrict__ bhh2,
    const float* __restrict__ fcw, const float* __restrict__ fcb,
    float* __restrict__ out) {
  __shared__ __align__(16) _Float16 h12[16][104];  // cols 0-47 h1, 48-95 h2
  __shared__ __align__(16) float gs1[8][196];      // L1 gate staging
  __shared__ __align__(16) float gs2[8][196];      // L2 gate staging
  __shared__ __align__(16) float h2f[8][52];       // h2 fp32 for fc_states
  __shared__ __align__(16) float fcws[5 * 48];
  __shared__ float logit_s[5][8];
  __shared__ float prob_s[5][8];
  __shared__ __align__(16) _Float16 pfhi[2][8][200];  // staged pf hi, [t][h] pad200
  __shared__ __align__(16) _Float16 pflo[2][8][200];  // staged pf lo

  const int tid = threadIdx.x;
  const int w = tid >> 6, l = tid & 63;
  const int lj = l & 15, lq = l >> 4;
  // XCD-aware bijective swizzle (nwg=512, 512%8==0, chunk=64): XCD x owns
  // groups [x*64, x*64+64) == batches 2x, 2x+1 -> same-b pf lines L2-dedupe.
  const int g512 = (blockIdx.x & 7) * 64 + (blockIdx.x >> 3);
  const int n0 = g512 * 8;
  const int b = n0 >> 8, t0 = n0 & 255;

  // ---- persistent weight B-fragments (f16): recurrent + input GEMM ----
  f16x8 b1[3][2];    // whh1 cols, K=48 pad 64
  f16x8 b2f[3][3];   // [wih2; whh2] cols, K=96
  f16x8 wf[3][6];    // wih1 feature cols, K=188 pad 192
  float bias2r[3];
#pragma unroll
  for (int i = 0; i < 3; ++i) {
    const int j = w * 48 + i * 16 + lj;
    bias2r[i] = bih2[j] + bhh2[j];
#pragma unroll
    for (int kc = 0; kc < 2; ++kc)
#pragma unroll
      for (int e = 0; e < 8; ++e) {
        const int u = kc * 32 + lq * 8 + e;
        b1[i][kc][e] = (u < U_) ? (_Float16)whh1[j * U_ + u] : (_Float16)0.f;
      }
#pragma unroll
    for (int kc = 0; kc < 3; ++kc)
#pragma unroll
      for (int e = 0; e < 8; ++e) {
        const int k = kc * 32 + lq * 8 + e;
        b2f[i][kc][e] = (k < U_) ? (_Float16)wih2[j * U_ + k]
                                 : (_Float16)whh2[j * U_ + (k - U_)];
      }
#pragma unroll
    for (int kc = 0; kc < 6; ++kc)
#pragma unroll
      for (int e = 0; e < 8; ++e) {
        const int k = kc * 32 + lq * 8 + e;
        wf[i][kc][e] = (k < H_) ? (_Float16)wih1[(size_t)j * G_ + k] : (_Float16)0.f;
      }
  }

  // ---- zero LDS state, load fc weights ----
  for (int e = tid; e < 16 * 104 / 2; e += 256) ((unsigned*)h12)[e] = 0u;
  for (int e = tid; e < 1600; e += 256) {  // 2*8*200 halves = 1600 uints each
    ((unsigned*)pfhi)[e] = 0u;
    ((unsigned*)pflo)[e] = 0u;
  }
  for (int e = tid; e < 5 * U_; e += 256) fcws[e] = fcw[e];
  lds_barrier();  // zeros complete before staging writes

  // activation tasks: 384 = 8n x 48u per layer; slot0 = tid, slot1 = 256+tid
  const int tn0 = tid / U_, tu0 = tid % U_;
  const int tn1 = (256 + tid) / U_, tu1 = (256 + tid) % U_;
  const bool has2 = (tid < 128);
  float c1s[2] = {0.f, 0.f}, c2s[2] = {0.f, 0.f};

  // aux roles (r13): fc tid 0-39, store 96-135, softmax 192-199
  const bool fcth = tid < 40;
  const int fk = tid >> 3, fn = tid & 7;
  const float fcbr = fcth ? fcb[fk] : 0.f;
  const bool stth = tid >= 96 && tid < 136;
  const int sk = (tid - 96) >> 3, sn = (tid - 96) & 7;
  const bool smth = tid >= 192 && tid < 200;
  const int smn = tid - 192;

  // ---- pf staging coords: thread covers (h = tid/8 + 32*it, t = t0 + tid%8) ----
  const int sh = tid >> 3, stl = tid & 7;
  const float* pfb = pf + (size_t)b * P_ * H_ * T_ + (size_t)sh * T_ + t0 + stl;

  // prologue: stage pf(0) -> buf0, pf(1) -> buf1
#pragma unroll
  for (int it = 0; it < 6; ++it) {
    const int h = sh + it * 32;
    if (h < H_) {
      const float v0 = pfb[(size_t)it * 32 * T_];
      const float v1 = pfb[(size_t)H_ * T_ + (size_t)it * 32 * T_];
      const _Float16 h0 = (_Float16)v0, h1 = (_Float16)v1;
      pfhi[0][stl][h] = h0; pflo[0][stl][h] = (_Float16)(v0 - (float)h0);
      pfhi[1][stl][h] = h1; pflo[1][stl][h] = (_Float16)(v1 - (float)h1);
    }
  }
  lds_barrier();

  // ctx-bias registers: cg for xg(0) now, cgN = cg(1) for first in-loop prod
  const float* cgbase = ctxg + (size_t)b * P_ * G_ + w * 48 + lj;
  float cgN[3];
  f32x4 xgC[3];
#pragma unroll
  for (int i = 0; i < 3; ++i) {
    const float c0 = cgbase[i * 16];
    xgC[i][0] = c0; xgC[i][1] = c0; xgC[i][2] = c0; xgC[i][3] = c0;
    cgN[i] = cgbase[G_ + i * 16];
  }
  const float* cgp = cgbase + 2 * G_;

#define INGEMM(ACC, RB)                                                        \
  {                                                                            \
    _Pragma("unroll") for (int c = 0; c < 6; ++c) {                            \
      const f16x8 ah = *(const f16x8*)&pfhi[RB][lj & 7][c * 32 + lq * 8];      \
      const f16x8 al = *(const f16x8*)&pflo[RB][lj & 7][c * 32 + lq * 8];      \
      ACC[0] = __builtin_amdgcn_mfma_f32_16x16x32_f16(ah, wf[0][c], ACC[0], 0, 0, 0); \
      ACC[1] = __builtin_amdgcn_mfma_f32_16x16x32_f16(ah, wf[1][c], ACC[1], 0, 0, 0); \
      ACC[2] = __builtin_amdgcn_mfma_f32_16x16x32_f16(ah, wf[2][c], ACC[2], 0, 0, 0); \
      ACC[0] = __builtin_amdgcn_mfma_f32_16x16x32_f16(al, wf[0][c], ACC[0], 0, 0, 0); \
      ACC[1] = __builtin_amdgcn_mfma_f32_16x16x32_f16(al, wf[1][c], ACC[1], 0, 0, 0); \
      ACC[2] = __builtin_amdgcn_mfma_f32_16x16x32_f16(al, wf[2][c], ACC[2], 0, 0, 0); \
    }                                                                          \
  }

  // prologue inGEMM: xgC = xg(0) from buf0
  INGEMM(xgC, 0);
  lds_barrier();  // all waves done reading buf0 before M(-1) re-stages it

  const float* pfstage = pfb + (size_t)2 * H_ * T_;  // pf(2) slice

  for (int p = -1; p < P_; ++p) {
    const bool doL2 = (p >= 0), doL1 = (p < P_ - 1);
    const bool doProd = (p <= 85), doStage = (p <= 84);
    const int prb = p & 1;          // inGEMM reads pf(p+2) from buf[p&1]
    const int pwb = prb ^ 1;        // stage pf(p+3) into the other buffer

    // ---- issue pf(p+3) global loads first (latency hides under MFMAs) ----
    float pv[6];
    if (doStage) {
#pragma unroll
      for (int it = 0; it < 6; ++it)
        pv[it] = (sh + it * 32 < H_) ? pfstage[(size_t)it * 32 * T_] : 0.f;
    }

    // ================= M: MFMA phase =================
    const _Float16* hr = &h12[lj][0];
    const f16x8 f0 = *(const f16x8*)(hr + lq * 8);        // h1 k0-31
    const f16x8 f1 = *(const f16x8*)(hr + 32 + lq * 8);   // h1/h2 k32-63
    if (doL2) {  // L2(p): K=96 over [h1(p); h2(p-1)]
      const f16x8 f2 = *(const f16x8*)(hr + 64 + lq * 8);
      f32x4 dH[3];
#pragma unroll
      for (int i = 0; i < 3; ++i) {
        dH[i][0] = bias2r[i]; dH[i][1] = bias2r[i];
        dH[i][2] = bias2r[i]; dH[i][3] = bias2r[i];
      }
#pragma unroll
      for (int i = 0; i < 3; ++i)
        dH[i] = __builtin_amdgcn_mfma_f32_16x16x32_f16(f0, b2f[i][0], dH[i], 0, 0, 0);
#pragma unroll
      for (int i = 0; i < 3; ++i)
        dH[i] = __builtin_amdgcn_mfma_f32_16x16x32_f16(f1, b2f[i][1], dH[i], 0, 0, 0);
#pragma unroll
      for (int i = 0; i < 3; ++i)
        dH[i] = __builtin_amdgcn_mfma_f32_16x16x32_f16(f2, b2f[i][2], dH[i], 0, 0, 0);
      if (lq < 2) {
#pragma unroll
        for (int i = 0; i < 3; ++i)
#pragma unroll
          for (int r = 0; r < 4; ++r)
            gs2[lq * 4 + r][w * 48 + i * 16 + lj] = dH[i][r];
      }
    }
    if (fcth && p >= 1) {  // fc logits of step p-1
      float a = fcbr;
#pragma unroll
      for (int uq = 0; uq < 12; ++uq) {
        f32x4 hv = *(const f32x4*)&h2f[fn][uq * 4];
        f32x4 wv = *(const f32x4*)&fcws[fk * 48 + uq * 4];
        a += hv[0] * wv[0] + hv[1] * wv[1] + hv[2] * wv[2] + hv[3] * wv[3];
      }
      logit_s[fk][fn] = a;
    }
    if (stth && p >= 2) {  // store probs of step p-2
      out[(((size_t)b * P_ + (p - 2)) * 5 + sk) * T_ + t0 + sn] = prob_s[sk][sn];
    }
    __builtin_amdgcn_sched_barrier(0);
    if (doL1) {  // L1(p+1): C = xgC (f32 xg(p+1), ctx bias included), K=48
      f32x4 cH[3];
#pragma unroll
      for (int i = 0; i < 3; ++i)
        cH[i] = __builtin_amdgcn_mfma_f32_16x16x32_f16(f0, b1[i][0], xgC[i], 0, 0, 0);
#pragma unroll
      for (int i = 0; i < 3; ++i)
        cH[i] = __builtin_amdgcn_mfma_f32_16x16x32_f16(f1, b1[i][1], cH[i], 0, 0, 0);
      if (lq < 2) {
#pragma unroll
        for (int i = 0; i < 3; ++i)
#pragma unroll
          for (int r = 0; r < 4; ++r)
            gs1[lq * 4 + r][w * 48 + i * 16 + lj] = cH[i][r];
      }
    }
    if (doProd) {  // inGEMM: xg(p+2) = ctx(p+2) + pf(p+2)·W (hi+lo terms)
      f32x4 xgP[3];
#pragma unroll
      for (int i = 0; i < 3; ++i) {
        xgP[i][0] = cgN[i]; xgP[i][1] = cgN[i];
        xgP[i][2] = cgN[i]; xgP[i][3] = cgN[i];
      }
      INGEMM(xgP, prb);
      if (doStage) {  // reload cgN = ctx(p+3)
#pragma unroll
        for (int i = 0; i < 3; ++i) cgN[i] = cgp[i * 16];
        cgp += G_;
      }
#pragma unroll
      for (int i = 0; i < 3; ++i) xgC[i] = xgP[i];
    }
    if (doStage) {  // convert + LDS-write pf(p+3) into buf[pwb]
#pragma unroll
      for (int it = 0; it < 6; ++it) {
        const int h = sh + it * 32;
        if (h < H_) {
          const _Float16 hi = (_Float16)pv[it];
          pfhi[pwb][stl][h] = hi;
          pflo[pwb][stl][h] = (_Float16)(pv[it] - (float)hi);
        }
      }
      pfstage += (size_t)H_ * T_;
    }
    lds_barrier();
    // ================= V: activation phase =================
    if (doL2) {  // act2(p) -> h2(p), h2f(p)
      {
        const int n = tn0, u = tu0;
        const float ig = gs2[n][u], fg = gs2[n][48 + u];
        const float gg = gs2[n][96 + u], og = gs2[n][144 + u];
        const float cc = sigf(fg) * c2s[0] + sigf(ig) * tanh_f(gg);
        c2s[0] = cc;
        const float h = sigf(og) * tanh_f(cc);
        h12[n][48 + u] = (_Float16)h;
        h2f[n][u] = h;
      }
      if (has2) {
        const int n = tn1, u = tu1;
        const float ig = gs2[n][u], fg = gs2[n][48 + u];
        const float gg = gs2[n][96 + u], og = gs2[n][144 + u];
        const float cc = sigf(fg) * c2s[1] + sigf(ig) * tanh_f(gg);
        c2s[1] = cc;
        const float h = sigf(og) * tanh_f(cc);
        h12[n][48 + u] = (_Float16)h;
        h2f[n][u] = h;
      }
    }
    if (doL1) {  // act1(p+1) -> h1(p+1)
      {
        const int n = tn0, u = tu0;
        const float ig = gs1[n][u], fg = gs1[n][48 + u];
        const float gg = gs1[n][96 + u], og = gs1[n][144 + u];
        const float cc = sigf(fg) * c1s[0] + sigf(ig) * tanh_f(gg);
        c1s[0] = cc;
        h12[n][u] = (_Float16)(sigf(og) * tanh_f(cc));
      }
      if (has2) {
        const int n = tn1, u = tu1;
        const float ig = gs1[n][u], fg = gs1[n][48 + u];
        const float gg = gs1[n][96 + u], og = gs1[n][144 + u];
        const float cc = sigf(fg) * c1s[1] + sigf(ig) * tanh_f(gg);
        c1s[1] = cc;
        h12[n][u] = (_Float16)(sigf(og) * tanh_f(cc));
      }
    }
    if (smth && p >= 1) {  // softmax of step p-1 (logits from M(p))
      const int n = smn;
      const float l0 = logit_s[0][n], l1 = logit_s[1][n], l2 = logit_s[2][n],
                  l3 = logit_s[3][n], l4 = logit_s[4][n];
      const float m = fmaxf(fmaxf(fmaxf(l0, l1), fmaxf(l2, l3)), l4);
      const float e0 = __expf(l0 - m), e1 = __expf(l1 - m), e2 = __expf(l2 - m),
                  e3 = __expf(l3 - m), e4 = __expf(l4 - m);
      const float rs = __builtin_amdgcn_rcpf(e0 + e1 + e2 + e3 + e4);
      prob_s[0][n] = e0 * rs; prob_s[1][n] = e1 * rs; prob_s[2][n] = e2 * rs;
      prob_s[3][n] = e3 * rs; prob_s[4][n] = e4 * rs;
    }
    lds_barrier();
  }
  // ---- epilogue: fc(87) + store(86); softmax(87); store(87) ----
  if (fcth) {
    float a = fcbr;
#pragma unroll
    for (int uq = 0; uq < 12; ++uq) {
      f32x4 hv = *(const f32x4*)&h2f[fn][uq * 4];
      f32x4 wv = *(const f32x4*)&fcws[fk * 48 + uq * 4];
      a += hv[0] * wv[0] + hv[1] * wv[1] + hv[2] * wv[2] + hv[3] * wv[3];
    }
    logit_s[fk][fn] = a;
  }
  if (stth) {
    out[(((size_t)b * P_ + (P_ - 2)) * 5 + sk) * T_ + t0 + sn] = prob_s[sk][sn];
  }
  lds_barrier();
  if (smth) {
    const int n = smn;
    const float l0 = logit_s[0][n], l1 = logit_s[1][n], l2 = logit_s[2][n],
                l3 = logit_s[3][n], l4 = logit_s[4][n];
    const float m = fmaxf(fmaxf(fmaxf(l0, l1), fmaxf(l2, l3)), l4);
    const float e0 = __expf(l0 - m), e1 = __expf(l1 - m), e2 = __expf(l2 - m),
                e3 = __expf(l3 - m), e4 = __expf(l4 - m);
    const float rs = __builtin_amdgcn_rcpf(e0 + e1 + e2 + e3 + e4);
    prob_s[0][n] = e0 * rs; prob_s[1][n] = e1 * rs; prob_s[2][n] = e2 * rs;
    prob_s[3][n] = e3 * rs; prob_s[4][n] = e4 * rs;
  }
  lds_barrier();
  if (stth) {
    out[(((size_t)b * P_ + (P_ - 1)) * 5 + sk) * T_ + t0 + sn] = prob_s[sk][sn];
  }
}

extern "C" void kernel_launch(void* const* d_in, const int* in_sizes, int n_in,
                              void* d_out, int out_size, void* d_ws, size_t ws_size,
                              hipStream_t stream) {
  const float* pf   = (const float*)d_in[0];
  const float* pc   = (const float*)d_in[1];
  const float* fc1w = (const float*)d_in[2];
  const float* fc1b = (const float*)d_in[3];
  const float* fc2w = (const float*)d_in[4];
  const float* fc2b = (const float*)d_in[5];
  const float* fc3w = (const float*)d_in[6];
  const float* fc3b = (const float*)d_in[7];
  const float* wih1 = (const float*)d_in[8];
  const float* whh1 = (const float*)d_in[9];
  const float* bih1 = (const float*)d_in[10];
  const float* bhh1 = (const float*)d_in[11];
  const float* wih2 = (const float*)d_in[12];
  const float* whh2 = (const float*)d_in[13];
  const float* bih2 = (const float*)d_in[14];
  const float* bhh2 = (const float*)d_in[15];
  const float* fcw  = (const float*)d_in[16];
  const float* fcb  = (const float*)d_in[17];
  float* out = (float*)d_out;

  float* ctxg = (float*)d_ws;  // (B*P) x 192 fp32 = ~1.08 MB

  ctx_kernel<<<22, 64, 0, stream>>>(pc, fc1w, fc1b, fc2w, fc2b, fc3w, fc3b,
                                    wih1, bih1, bhh1, ctxg);
  scan_fused<<<N_ / 8, 256, 0, stream>>>(pf, ctxg, wih1, whh1, wih2, whh2,
                                         bih2, bhh2, fcw, fcb, out);
}

// Round 18
// 366.998 us; speedup vs baseline: 1.3288x; 1.0690x over previous
//
#include <hip/hip_runtime.h>
#include <hip/hip_bf16.h>
#include <cstdint>

#define P_ 88   // pitches (sequence length of the scan)
#define B_ 16   // batch
#define T_ 256  // timesteps (folded into batch N)
#define H_ 188  // per-pitch features
#define G_ 192  // 4*48 gates; also LSTM1 input size (188 feat + 4 ctx)
#define U_ 48   // LSTM units
#define N_ 4096 // B_*T_

typedef __attribute__((ext_vector_type(8))) _Float16 f16x8;
typedef __attribute__((ext_vector_type(4))) float f32x4;

__device__ __forceinline__ float sigf(float x) {
  return __builtin_amdgcn_rcpf(1.0f + __expf(-x));
}
__device__ __forceinline__ float tanh_f(float x) {
  return 1.0f - 2.0f * __builtin_amdgcn_rcpf(1.0f + __expf(2.0f * x));
}

// Relaxed workgroup barrier: waits only on LDS ops (lgkmcnt), NOT vmcnt.
__device__ __forceinline__ void lds_barrier() {
  asm volatile("s_waitcnt lgkmcnt(0)\n\ts_barrier" ::: "memory");
}

// ---------------------------------------------------------------------------
// Kernel 1: context MLP -> per-(b,p) gate bias vector (incl. bih1+bhh1).
// ---------------------------------------------------------------------------
__global__ void ctx_kernel(const float* __restrict__ pc,
                           const float* __restrict__ fc1w, const float* __restrict__ fc1b,
                           const float* __restrict__ fc2w, const float* __restrict__ fc2b,
                           const float* __restrict__ fc3w, const float* __restrict__ fc3b,
                           const float* __restrict__ wih1,
                           const float* __restrict__ bih1, const float* __restrict__ bhh1,
                           float* __restrict__ ctxg) {
  int bp = blockIdx.x * 64 + threadIdx.x;
  if (bp >= B_ * P_) return;
  float p0 = pc[bp * 3 + 0], p1 = pc[bp * 3 + 1], p2 = pc[bp * 3 + 2];
  float x1[16], x2[16];
#pragma unroll
  for (int jj = 0; jj < 16; ++jj)
    x1[jj] = fmaxf(0.f, fc1w[jj * 3 + 0] * p0 + fc1w[jj * 3 + 1] * p1 + fc1w[jj * 3 + 2] * p2 + fc1b[jj]);
#pragma unroll
  for (int jj = 0; jj < 16; ++jj) {
    float s = fc2b[jj];
#pragma unroll
    for (int i = 0; i < 16; ++i) s += fc2w[jj * 16 + i] * x1[i];
    x2[jj] = fmaxf(0.f, s);
  }
  float ce[4];
#pragma unroll
  for (int jj = 0; jj < 4; ++jj) {
    float s = fc3b[jj];
#pragma unroll
    for (int i = 0; i < 16; ++i) s += fc3w[jj * 16 + i] * x2[i];
    ce[jj] = s;
  }
  float* op = ctxg + (size_t)bp * G_;
  for (int g = 0; g < G_; ++g) {
    const float* wr = wih1 + (size_t)g * G_ + H_;
    op[g] = bih1[g] + bhh1[g] + ce[0] * wr[0] + ce[1] * wr[1] + ce[2] * wr[2] + ce[3] * wr[3];
  }
}

// ---------------------------------------------------------------------------
// Kernel 2: FUSED scan + PAIRED input GEMM + XCD swizzle.
// inGEMM now packs TWO p-slices per 16x16 MFMA tile (A rows 0-7 = even
// slice, 8-15 = odd slice): one INGEMM per 2 steps, halving inGEMM MFMAs
// and LDS reads per step at zero precision cost. Odd-slice xg moves to
// consumer lanes via shfl_xor(32).
// ---------------------------------------------------------------------------
__global__ __launch_bounds__(256, 2) void scan_fused(
    const float* __restrict__ pf, const float* __restrict__ ctxg,
    const float* __restrict__ wih1, const float* __restrict__ whh1,
    const float* __restrict__ wih2, const float* __restrict__ whh2,
    const float* __restrict__ bih2, const float* __restrict__ bhh2,
    const float* __restrict__ fcw, const float* __restrict__ fcb,
    float* __restrict__ out) {
  __shared__ __align__(16) _Float16 h12[16][104];  // cols 0-47 h1, 48-95 h2
  __shared__ __align__(16) float gs1[8][196];      // L1 gate staging
  __shared__ __align__(16) float gs2[8][196];      // L2 gate staging
  __shared__ __align__(16) float h2f[8][52];       // h2 fp32 for fc_states
  __shared__ __align__(16) float fcws[5 * 48];
  __shared__ float logit_s[5][8];
  __shared__ float prob_s[5][8];
  // pf pair buffers: rows 0-7 = even slice, rows 8-15 = odd slice of pair m;
  // buffer index = m & 1.
  __shared__ __align__(16) _Float16 pfhi[2][16][200];
  __shared__ __align__(16) _Float16 pflo[2][16][200];

  const int tid = threadIdx.x;
  const int w = tid >> 6, l = tid & 63;
  const int lj = l & 15, lq = l >> 4;
  // XCD-aware bijective swizzle (512 blocks, chunk 64): XCD x owns batches
  // 2x, 2x+1 -> same-b scattered pf reads dedupe in that XCD's L2.
  const int g512 = (blockIdx.x & 7) * 64 + (blockIdx.x >> 3);
  const int n0 = g512 * 8;
  const int b = n0 >> 8, t0 = n0 & 255;

  // ---- persistent weight B-fragments (f16): recurrent + input GEMM ----
  f16x8 b1[3][2];    // whh1 cols, K=48 pad 64
  f16x8 b2f[3][3];   // [wih2; whh2] cols, K=96
  f16x8 wf[3][6];    // wih1 feature cols, K=188 pad 192
  float bias2r[3];
#pragma unroll
  for (int i = 0; i < 3; ++i) {
    const int j = w * 48 + i * 16 + lj;
    bias2r[i] = bih2[j] + bhh2[j];
#pragma unroll
    for (int kc = 0; kc < 2; ++kc)
#pragma unroll
      for (int e = 0; e < 8; ++e) {
        const int u = kc * 32 + lq * 8 + e;
        b1[i][kc][e] = (u < U_) ? (_Float16)whh1[j * U_ + u] : (_Float16)0.f;
      }
#pragma unroll
    for (int kc = 0; kc < 3; ++kc)
#pragma unroll
      for (int e = 0; e < 8; ++e) {
        const int k = kc * 32 + lq * 8 + e;
        b2f[i][kc][e] = (k < U_) ? (_Float16)wih2[j * U_ + k]
                                 : (_Float16)whh2[j * U_ + (k - U_)];
      }
#pragma unroll
    for (int kc = 0; kc < 6; ++kc)
#pragma unroll
      for (int e = 0; e < 8; ++e) {
        const int k = kc * 32 + lq * 8 + e;
        wf[i][kc][e] = (k < H_) ? (_Float16)wih1[(size_t)j * G_ + k] : (_Float16)0.f;
      }
  }

  // ---- zero LDS state, load fc weights ----
  for (int e = tid; e < 16 * 104 / 2; e += 256) ((unsigned*)h12)[e] = 0u;
  for (int e = tid; e < 3200; e += 256) {  // 2*16*200 halves = 3200 uints each
    ((unsigned*)pfhi)[e] = 0u;
    ((unsigned*)pflo)[e] = 0u;
  }
  for (int e = tid; e < 5 * U_; e += 256) fcws[e] = fcw[e];
  lds_barrier();  // zeros complete before staging writes

  // activation tasks: 384 = 8n x 48u per layer; slot0 = tid, slot1 = 256+tid
  const int tn0 = tid / U_, tu0 = tid % U_;
  const int tn1 = (256 + tid) / U_, tu1 = (256 + tid) % U_;
  const bool has2 = (tid < 128);
  float c1s[2] = {0.f, 0.f}, c2s[2] = {0.f, 0.f};

  // aux roles: fc tid 0-39, store 96-135, softmax 192-199
  const bool fcth = tid < 40;
  const int fk = tid >> 3, fn = tid & 7;
  const float fcbr = fcth ? fcb[fk] : 0.f;
  const bool stth = tid >= 96 && tid < 136;
  const int sk = (tid - 96) >> 3, sn = (tid - 96) & 7;
  const bool smth = tid >= 192 && tid < 200;
  const int smn = tid - 192;

  // ---- pf staging coords: thread covers (h = tid/8 + 32*it, t = t0 + tid%8) ----
  const int sh = tid >> 3, stl = tid & 7;
  const float* pfb = pf + (size_t)b * P_ * H_ * T_ + (size_t)sh * T_ + t0 + stl;

  // prologue: stage slices 0,1 -> buf0 rows {0-7},{8-15}; slices 2,3 -> buf1
#pragma unroll
  for (int s = 0; s < 4; ++s) {
    const int bufi = (s >> 1) & 1, row = (s & 1) * 8 + stl;
    const float* sp = pfb + (size_t)s * H_ * T_;
#pragma unroll
    for (int it = 0; it < 6; ++it) {
      const int h = sh + it * 32;
      if (h < H_) {
        const float v = sp[(size_t)it * 32 * T_];
        const _Float16 hi = (_Float16)v;
        pfhi[bufi][row][h] = hi;
        pflo[bufi][row][h] = (_Float16)(v - (float)hi);
      }
    }
  }
  lds_barrier();

  // ctx-bias pointer (gate column w*48+i*16+lj)
  const float* cgbase = ctxg + (size_t)b * P_ * G_ + w * 48 + lj;

// INGEMM over pair buffer RB: C init = per-lane-half biases (CE/CO arrays)
#define INGEMM(ACC, RB, CE, CO)                                                \
  {                                                                            \
    _Pragma("unroll") for (int i = 0; i < 3; ++i) {                            \
      const float bsel = (l < 32) ? (CE)[i] : (CO)[i];                         \
      ACC[i][0] = bsel; ACC[i][1] = bsel; ACC[i][2] = bsel; ACC[i][3] = bsel;  \
    }                                                                          \
    _Pragma("unroll") for (int c = 0; c < 6; ++c) {                            \
      const f16x8 ah = *(const f16x8*)&pfhi[RB][lj][c * 32 + lq * 8];          \
      const f16x8 al = *(const f16x8*)&pflo[RB][lj][c * 32 + lq * 8];          \
      ACC[0] = __builtin_amdgcn_mfma_f32_16x16x32_f16(ah, wf[0][c], ACC[0], 0, 0, 0); \
      ACC[1] = __builtin_amdgcn_mfma_f32_16x16x32_f16(ah, wf[1][c], ACC[1], 0, 0, 0); \
      ACC[2] = __builtin_amdgcn_mfma_f32_16x16x32_f16(ah, wf[2][c], ACC[2], 0, 0, 0); \
      ACC[0] = __builtin_amdgcn_mfma_f32_16x16x32_f16(al, wf[0][c], ACC[0], 0, 0, 0); \
      ACC[1] = __builtin_amdgcn_mfma_f32_16x16x32_f16(al, wf[1][c], ACC[1], 0, 0, 0); \
      ACC[2] = __builtin_amdgcn_mfma_f32_16x16x32_f16(al, wf[2][c], ACC[2], 0, 0, 0); \
    }                                                                          \
  }

  // prologue production: pair 0 -> xgA = xg(0) (lanes l<32), xgB = xg(1)
  f32x4 xgA[3], xgB[3];
  {
    float cgE[3], cgO[3];
#pragma unroll
    for (int i = 0; i < 3; ++i) { cgE[i] = cgbase[i * 16]; cgO[i] = cgbase[G_ + i * 16]; }
    f32x4 xgP[3];
    INGEMM(xgP, 0, cgE, cgO);
#pragma unroll
    for (int i = 0; i < 3; ++i) {
      xgA[i] = xgP[i];
#pragma unroll
      for (int r = 0; r < 4; ++r) xgB[i][r] = __shfl_xor((float)xgP[i][r], 32);
    }
  }
  lds_barrier();  // buf0 reads complete before iter-0 staging rewrites it

  const float* cgp = cgbase + 2 * G_;                 // ctx(2) onward
  const float* pfstage = pfb + (size_t)4 * H_ * T_;   // slice 4 onward

  for (int p = -1; p < P_; ++p) {
    const bool doL2 = (p >= 0), doL1 = (p < P_ - 1);
    const bool doProd = ((p & 1) == 0) && (p <= 84);   // pair (p+2, p+3)
    const bool doStage = (p >= 0 && p <= 83);          // slice p+4
    const int prodRB = ((p + 2) >> 1) & 1;
    const int stgRB = ((p + 4) >> 1) & 1, stgRow = ((p + 4) & 1) * 8 + stl;

    // ---- issue pf(p+4) global loads early (latency hides under MFMAs) ----
    float pv[6];
    if (doStage) {
#pragma unroll
      for (int it = 0; it < 6; ++it)
        pv[it] = (sh + it * 32 < H_) ? pfstage[(size_t)it * 32 * T_] : 0.f;
    }

    // ================= M: MFMA phase =================
    const _Float16* hr = &h12[lj][0];
    const f16x8 f0 = *(const f16x8*)(hr + lq * 8);        // h1 k0-31
    const f16x8 f1 = *(const f16x8*)(hr + 32 + lq * 8);   // h1/h2 k32-63
    if (doL2) {  // L2(p): K=96 over [h1(p); h2(p-1)]
      const f16x8 f2 = *(const f16x8*)(hr + 64 + lq * 8);
      f32x4 dH[3];
#pragma unroll
      for (int i = 0; i < 3; ++i) {
        dH[i][0] = bias2r[i]; dH[i][1] = bias2r[i];
        dH[i][2] = bias2r[i]; dH[i][3] = bias2r[i];
      }
#pragma unroll
      for (int i = 0; i < 3; ++i)
        dH[i] = __builtin_amdgcn_mfma_f32_16x16x32_f16(f0, b2f[i][0], dH[i], 0, 0, 0);
#pragma unroll
      for (int i = 0; i < 3; ++i)
        dH[i] = __builtin_amdgcn_mfma_f32_16x16x32_f16(f1, b2f[i][1], dH[i], 0, 0, 0);
#pragma unroll
      for (int i = 0; i < 3; ++i)
        dH[i] = __builtin_amdgcn_mfma_f32_16x16x32_f16(f2, b2f[i][2], dH[i], 0, 0, 0);
      if (lq < 2) {
#pragma unroll
        for (int i = 0; i < 3; ++i)
#pragma unroll
          for (int r = 0; r < 4; ++r)
            gs2[lq * 4 + r][w * 48 + i * 16 + lj] = dH[i][r];
      }
    }
    if (fcth && p >= 1) {  // fc logits of step p-1
      float a = fcbr;
#pragma unroll
      for (int uq = 0; uq < 12; ++uq) {
        f32x4 hv = *(const f32x4*)&h2f[fn][uq * 4];
        f32x4 wv = *(const f32x4*)&fcws[fk * 48 + uq * 4];
        a += hv[0] * wv[0] + hv[1] * wv[1] + hv[2] * wv[2] + hv[3] * wv[3];
      }
      logit_s[fk][fn] = a;
    }
    if (stth && p >= 2) {  // store probs of step p-2
      out[(((size_t)b * P_ + (p - 2)) * 5 + sk) * T_ + t0 + sn] = prob_s[sk][sn];
    }
    __builtin_amdgcn_sched_barrier(0);
    if (doL1) {  // L1(p+1): C = xg(p+1) (xgA if p odd, xgB if p even), K=48
      f32x4 cH[3];
#pragma unroll
      for (int i = 0; i < 3; ++i) {
        const f32x4 xc = (p & 1) ? xgA[i] : xgB[i];
        cH[i] = __builtin_amdgcn_mfma_f32_16x16x32_f16(f0, b1[i][0], xc, 0, 0, 0);
      }
#pragma unroll
      for (int i = 0; i < 3; ++i)
        cH[i] = __builtin_amdgcn_mfma_f32_16x16x32_f16(f1, b1[i][1], cH[i], 0, 0, 0);
      if (lq < 2) {
#pragma unroll
        for (int i = 0; i < 3; ++i)
#pragma unroll
          for (int r = 0; r < 4; ++r)
            gs1[lq * 4 + r][w * 48 + i * 16 + lj] = cH[i][r];
      }
    }
    if (doProd) {  // paired inGEMM: xg(p+2) & xg(p+3) in one pass
      float cgE[3], cgO[3];
#pragma unroll
      for (int i = 0; i < 3; ++i) { cgE[i] = cgp[i * 16]; cgO[i] = cgp[G_ + i * 16]; }
      cgp += 2 * G_;
      f32x4 xgP[3];
      INGEMM(xgP, prodRB, cgE, cgO);
#pragma unroll
      for (int i = 0; i < 3; ++i) {
        xgA[i] = xgP[i];
#pragma unroll
        for (int r = 0; r < 4; ++r) xgB[i][r] = __shfl_xor((float)xgP[i][r], 32);
      }
    }
    if (doStage) {  // convert + LDS-write pf(p+4)
#pragma unroll
      for (int it = 0; it < 6; ++it) {
        const int h = sh + it * 32;
        if (h < H_) {
          const _Float16 hi = (_Float16)pv[it];
          pfhi[stgRB][stgRow][h] = hi;
          pflo[stgRB][stgRow][h] = (_Float16)(pv[it] - (float)hi);
        }
      }
      pfstage += (size_t)H_ * T_;
    }
    lds_barrier();
    // ================= V: activation phase =================
    if (doL2) {  // act2(p) -> h2(p), h2f(p)
      {
        const int n = tn0, u = tu0;
        const float ig = gs2[n][u], fg = gs2[n][48 + u];
        const float gg = gs2[n][96 + u], og = gs2[n][144 + u];
        const float cc = sigf(fg) * c2s[0] + sigf(ig) * tanh_f(gg);
        c2s[0] = cc;
        const float h = sigf(og) * tanh_f(cc);
        h12[n][48 + u] = (_Float16)h;
        h2f[n][u] = h;
      }
      if (has2) {
        const int n = tn1, u = tu1;
        const float ig = gs2[n][u], fg = gs2[n][48 + u];
        const float gg = gs2[n][96 + u], og = gs2[n][144 + u];
        const float cc = sigf(fg) * c2s[1] + sigf(ig) * tanh_f(gg);
        c2s[1] = cc;
        const float h = sigf(og) * tanh_f(cc);
        h12[n][48 + u] = (_Float16)h;
        h2f[n][u] = h;
      }
    }
    if (doL1) {  // act1(p+1) -> h1(p+1)
      {
        const int n = tn0, u = tu0;
        const float ig = gs1[n][u], fg = gs1[n][48 + u];
        const float gg = gs1[n][96 + u], og = gs1[n][144 + u];
        const float cc = sigf(fg) * c1s[0] + sigf(ig) * tanh_f(gg);
        c1s[0] = cc;
        h12[n][u] = (_Float16)(sigf(og) * tanh_f(cc));
      }
      if (has2) {
        const int n = tn1, u = tu1;
        const float ig = gs1[n][u], fg = gs1[n][48 + u];
        const float gg = gs1[n][96 + u], og = gs1[n][144 + u];
        const float cc = sigf(fg) * c1s[1] + sigf(ig) * tanh_f(gg);
        c1s[1] = cc;
        h12[n][u] = (_Float16)(sigf(og) * tanh_f(cc));
      }
    }
    if (smth && p >= 1) {  // softmax of step p-1 (logits from M(p))
      const int n = smn;
      const float l0 = logit_s[0][n], l1 = logit_s[1][n], l2 = logit_s[2][n],
                  l3 = logit_s[3][n], l4 = logit_s[4][n];
      const float m = fmaxf(fmaxf(fmaxf(l0, l1), fmaxf(l2, l3)), l4);
      const float e0 = __expf(l0 - m), e1 = __expf(l1 - m), e2 = __expf(l2 - m),
                  e3 = __expf(l3 - m), e4 = __expf(l4 - m);
      const float rs = __builtin_amdgcn_rcpf(e0 + e1 + e2 + e3 + e4);
      prob_s[0][n] = e0 * rs; prob_s[1][n] = e1 * rs; prob_s[2][n] = e2 * rs;
      prob_s[3][n] = e3 * rs; prob_s[4][n] = e4 * rs;
    }
    lds_barrier();
  }
  // ---- epilogue: fc(87) + store(86); softmax(87); store(87) ----
  if (fcth) {
    float a = fcbr;
#pragma unroll
    for (int uq = 0; uq < 12; ++uq) {
      f32x4 hv = *(const f32x4*)&h2f[fn][uq * 4];
      f32x4 wv = *(const f32x4*)&fcws[fk * 48 + uq * 4];
      a += hv[0] * wv[0] + hv[1] * wv[1] + hv[2] * wv[2] + hv[3] * wv[3];
    }
    logit_s[fk][fn] = a;
  }
  if (stth) {
    out[(((size_t)b * P_ + (P_ - 2)) * 5 + sk) * T_ + t0 + sn] = prob_s[sk][sn];
  }
  lds_barrier();
  if (smth) {
    const int n = smn;
    const float l0 = logit_s[0][n], l1 = logit_s[1][n], l2 = logit_s[2][n],
                l3 = logit_s[3][n], l4 = logit_s[4][n];
    const float m = fmaxf(fmaxf(fmaxf(l0, l1), fmaxf(l2, l3)), l4);
    const float e0 = __expf(l0 - m), e1 = __expf(l1 - m), e2 = __expf(l2 - m),
                e3 = __expf(l3 - m), e4 = __expf(l4 - m);
    const float rs = __builtin_amdgcn_rcpf(e0 + e1 + e2 + e3 + e4);
    prob_s[0][n] = e0 * rs; prob_s[1][n] = e1 * rs; prob_s[2][n] = e2 * rs;
    prob_s[3][n] = e3 * rs; prob_s[4][n] = e4 * rs;
  }
  lds_barrier();
  if (stth) {
    out[(((size_t)b * P_ + (P_ - 1)) * 5 + sk) * T_ + t0 + sn] = prob_s[sk][sn];
  }
}

extern "C" void kernel_launch(void* const* d_in, const int* in_sizes, int n_in,
                              void* d_out, int out_size, void* d_ws, size_t ws_size,
                              hipStream_t stream) {
  const float* pf   = (const float*)d_in[0];
  const float* pc   = (const float*)d_in[1];
  const float* fc1w = (const float*)d_in[2];
  const float* fc1b = (const float*)d_in[3];
  const float* fc2w = (const float*)d_in[4];
  const float* fc2b = (const float*)d_in[5];
  const float* fc3w = (const float*)d_in[6];
  const float* fc3b = (const float*)d_in[7];
  const float* wih1 = (const float*)d_in[8];
  const float* whh1 = (const float*)d_in[9];
  const float* bih1 = (const float*)d_in[10];
  const float* bhh1 = (const float*)d_in[11];
  const float* wih2 = (const float*)d_in[12];
  const float* whh2 = (const float*)d_in[13];
  const float* bih2 = (const float*)d_in[14];
  const float* bhh2 = (const float*)d_in[15];
  const float* fcw  = (const float*)d_in[16];
  const float* fcb  = (const float*)d_in[17];
  float* out = (float*)d_out;

  float* ctxg = (float*)d_ws;  // (B*P) x 192 fp32 = ~1.08 MB

  ctx_kernel<<<22, 64, 0, stream>>>(pc, fc1w, fc1b, fc2w, fc2b, fc3w, fc3b,
                                    wih1, bih1, bhh1, ctxg);
  scan_fused<<<N_ / 8, 256, 0, stream>>>(pf, ctxg, wih1, whh1, wih2, whh2,
                                         bih2, bhh2, fcw, fcb, out);
}